// Round 8
// baseline (43446.292 us; speedup 1.0000x reference)
//
#include <hip/hip_runtime.h>
#include <float.h>
#include <math.h>

#define BB 2
#define CC 128
#define NN 4096
#define KNB 32
#define KSEL 34
#define MSEL 2048
#define NDROP 2048

// ---------------- workspace layout (bytes) ----------------
#define WS_WTQ    0
#define WS_WTV    (WS_WTQ + CC*CC*4)
#define WS_SQ     (WS_WTV + CC*CC*4)                 // double[BB*NN]
#define WS_SQF    (WS_SQ + BB*NN*8)                  // float[BB*NN]
#define WS_QT     (WS_SQF + BB*NN*4)                 // float[BB*NN*CC]
#define WS_VXT    (WS_QT  + BB*NN*CC*4)              // float[BB*NN*CC]
#define WS_KNN    (WS_VXT + BB*NN*CC*4)              // int
#define WS_ATTNF  (WS_KNN + BB*NN*KNB*4)             // float
#define WS_STD    (WS_ATTNF + BB*NN*KNB*4)           // float[BB*NN]
#define WS_SCORE  (WS_STD + BB*NN*4)                 // float[BB*NN]
#define WS_COUNTS (WS_SCORE + BB*NN*4)
#define WS_CURSOR (WS_COUNTS + BB*NN*4)
#define WS_OFF    (WS_CURSOR + BB*NN*4)
#define WS_SLOTS  (WS_OFF + BB*NN*4)
#define WS_SELDS  (WS_SLOTS + BB*NN*KNB*4)
#define WS_SELDR  (WS_SELDS + BB*MSEL*4)
#define WS_END    (WS_SELDR + BB*NDROP*4)

// ---------------- output layout (floats) ----------------
#define OUT_XDS  0
#define OUT_IDX  (BB*CC*MSEL)
#define OUT_XDR  (OUT_IDX + BB*MSEL)
#define OUT_IDXD (OUT_XDR + BB*CC*NDROP)

// XLA:CPU-style sequential reduction over 32 contiguous fp32 (unfused adds).
__device__ __forceinline__ float seq32(const float* a) {
    float acc = a[0];
    #pragma unroll
    for (int i = 1; i < 32; ++i) acc = __fadd_rn(acc, a[i]);
    return acc;
}

// XLA lowers exp -> libm expf (nearly correctly rounded): emulate via double.
__device__ __forceinline__ float xla_expf(float x) {
    return (float)exp((double)x);
}

__global__ void k_transposeW(const float* __restrict__ Wq, const float* __restrict__ Wv,
                             float* __restrict__ WTq, float* __restrict__ WTv) {
    int c = blockIdx.x, o = threadIdx.x;
    WTq[c*CC + o] = Wq[o*CC + c];
    WTv[c*CC + o] = Wv[o*CC + c];
}

// sqD: fp64 (robust candidate selection). sqF: fp32 sequential (ref-emu).
__global__ void k_sq(const float* __restrict__ x, double* __restrict__ sqD,
                     float* __restrict__ sqF) {
    int i = blockIdx.x*blockDim.x + threadIdx.x;
    if (i >= BB*NN) return;
    int b = i / NN, n = i % NN;
    const float* xb = x + (size_t)b*CC*NN;
    double s = 0.0;
    float sf = 0.f;
    for (int c = 0; c < CC; ++c) {
        float v = xb[(size_t)c*NN + n];
        s += (double)v * (double)v;
        sf = __fadd_rn(sf, __fmul_rn(v, v));
    }
    sqD[i] = s; sqF[i] = sf;
}

// q: XLA-emu (sequential over c, FMA). v: plain fp32 (lenient outputs).
__global__ __launch_bounds__(CC) void k_proj(const float* __restrict__ x,
                                             const float* __restrict__ WTq,
                                             const float* __restrict__ WTv,
                                             float* __restrict__ qT,
                                             float* __restrict__ vxT) {
    int bn = blockIdx.x;
    int b = bn / NN, n = bn % NN;
    int o = threadIdx.x;
    __shared__ float xs[CC];
    xs[o] = x[(size_t)b*CC*NN + (size_t)o*NN + n];
    __syncthreads();
    float aq = 0.f, av = 0.f;
    for (int c = 0; c < CC; ++c) {
        float xv = xs[c];
        aq = fmaf(WTq[c*CC + o], xv, aq);
        av = fmaf(WTv[c*CC + o], xv, av);
    }
    size_t base = (size_t)bn*CC + o;
    qT[base] = aq; vxT[base] = av;
}

// KNN: fp64 selection of top-KSEL, then re-rank by fp32 dist with stable
// index tie-break (matches ref fp32 ordering at quantization ties).
__global__ __launch_bounds__(256) void k_knn(const float* __restrict__ x,
                                             const double* __restrict__ sqD,
                                             const float* __restrict__ sqF,
                                             int* __restrict__ knn) {
    __shared__ double xs[CC];
    __shared__ double dist[NN];
    __shared__ double rv[4];
    __shared__ int   ri[4];
    __shared__ int   selIdx[KSEL];
    __shared__ float selDist[KSEL];
    int b = blockIdx.x / NN;
    int n = blockIdx.x % NN;
    int tid = threadIdx.x;
    const float*  xb  = x   + (size_t)b*CC*NN;
    const double* sqb = sqD + b*NN;
    const float*  sqf = sqF + b*NN;
    for (int c = tid; c < CC; c += 256) xs[c] = (double)xb[(size_t)c*NN + n];
    __syncthreads();
    double sqn = sqb[n];
    for (int m = tid; m < NN; m += 256) {
        double acc = 0.0;
        for (int c = 0; c < CC; ++c) acc += xs[c] * (double)xb[(size_t)c*NN + m];
        dist[m] = (sqn + sqb[m]) - 2.0*acc;
    }
    __syncthreads();
    int wid = tid >> 6, lane = tid & 63;
    for (int kk = 0; kk < KSEL; ++kk) {
        double bv = DBL_MAX; int bi = NN;
        for (int m = tid; m < NN; m += 256) {
            double v = dist[m];
            if (v < bv || (v == bv && m < bi)) { bv = v; bi = m; }
        }
        for (int off = 32; off > 0; off >>= 1) {
            double ov = __shfl_down(bv, off);
            int    oi = __shfl_down(bi, off);
            if (ov < bv || (ov == bv && oi < bi)) { bv = ov; bi = oi; }
        }
        if (lane == 0) { rv[wid] = bv; ri[wid] = bi; }
        __syncthreads();
        if (tid == 0) {
            double fv = rv[0]; int fi = ri[0];
            for (int w = 1; w < 4; ++w)
                if (rv[w] < fv || (rv[w] == fv && ri[w] < fi)) { fv = rv[w]; fi = ri[w]; }
            selIdx[kk] = fi;
            dist[fi] = DBL_MAX;
        }
        __syncthreads();
    }
    if (tid < KSEL) {
        int m = selIdx[tid];
        float acc = 0.f;
        for (int c = 0; c < CC; ++c)
            acc = __fadd_rn(acc, __fmul_rn((float)xs[c], xb[(size_t)c*NN + m]));
        selDist[tid] = __fsub_rn(__fadd_rn(sqf[n], sqf[m]), __fmul_rn(2.0f, acc));
    }
    __syncthreads();
    if (tid == 0) {
        for (int a = 1; a < KSEL; ++a) {
            float dv = selDist[a]; int iv = selIdx[a]; int j = a-1;
            while (j >= 0 && (selDist[j] > dv || (selDist[j] == dv && selIdx[j] > iv))) {
                selDist[j+1] = selDist[j]; selIdx[j+1] = selIdx[j]; --j;
            }
            selDist[j+1] = dv; selIdx[j+1] = iv;
        }
        for (int kk = 0; kk < KNB; ++kk)
            knn[(size_t)blockIdx.x*KNB + kk] = selIdx[kk];
    }
}

// XLA-emu of k = Wk @ (x_m - x_n), energy = q . k (sequential FMA), then
// softmax + std with SEQUENTIAL 32-length reductions (XLA reduce order).
__global__ __launch_bounds__(CC) void k_energy(const float* __restrict__ x,
                                               const float* __restrict__ qT,
                                               const float* __restrict__ Wk,
                                               const int* __restrict__ knn,
                                               float* __restrict__ attnF,
                                               float* __restrict__ stdF) {
    int bn = blockIdx.x;
    int b = bn / NN, n = bn % NN;
    int o = threadIdx.x;
    __shared__ float xn[CC];
    __shared__ float qs[CC];
    __shared__ int   mIdx[KNB];
    __shared__ float nb[KNB][CC];
    __shared__ float kmat[KNB][CC];
    __shared__ float es[KNB];
    const float* xb = x + (size_t)b*CC*NN;
    xn[o] = xb[(size_t)o*NN + n];
    qs[o] = qT[(size_t)bn*CC + o];
    if (o < KNB) mIdx[o] = knn[(size_t)bn*KNB + o];
    __syncthreads();
    #pragma unroll
    for (int kk = 0; kk < KNB; ++kk)
        nb[kk][o] = __fsub_rn(xb[(size_t)o*NN + mIdx[kk]], xn[o]);
    __syncthreads();
    float acc[KNB];
    #pragma unroll
    for (int kk = 0; kk < KNB; ++kk) acc[kk] = 0.f;
    const float* wrow = Wk + (size_t)o*CC;
    for (int c = 0; c < CC; ++c) {
        float w = wrow[c];
        #pragma unroll
        for (int kk = 0; kk < KNB; ++kk)
            acc[kk] = fmaf(w, nb[kk][c], acc[kk]);
    }
    #pragma unroll
    for (int kk = 0; kk < KNB; ++kk) kmat[kk][o] = acc[kk];
    __syncthreads();
    if (o < KNB) {
        float e = 0.f;
        for (int d = 0; d < CC; ++d)
            e = fmaf(qs[d], kmat[o][d], e);
        es[o] = __fdiv_rn(e, __fsqrt_rn(128.0f));
    }
    __syncthreads();
    if (o == 0) {
        float mx = es[0];
        #pragma unroll
        for (int kk = 1; kk < KNB; ++kk) mx = fmaxf(mx, es[kk]);
        float p[KNB], a[KNB], d2[KNB];
        #pragma unroll
        for (int kk = 0; kk < KNB; ++kk)
            p[kk] = xla_expf(__fsub_rn(es[kk], mx));
        float s = seq32(p);
        #pragma unroll
        for (int kk = 0; kk < KNB; ++kk) {
            a[kk] = __fdiv_rn(p[kk], s);
            attnF[(size_t)bn*KNB + kk] = a[kk];
        }
        float mean = __fdiv_rn(seq32(a), 32.0f);
        #pragma unroll
        for (int kk = 0; kk < KNB; ++kk) {
            float dd = __fsub_rn(a[kk], mean);
            d2[kk] = __fmul_rn(dd, dd);
        }
        float var = __fdiv_rn(seq32(d2), 32.0f);
        stdF[bn] = __fsqrt_rn(var);
    }
}

__global__ void k_count(const int* __restrict__ knn, int* __restrict__ counts) {
    int i = blockIdx.x*blockDim.x + threadIdx.x;
    if (i >= BB*NN*KNB) return;
    int b = i / (NN*KNB);
    atomicAdd(&counts[b*NN + knn[i]], 1);
}

__global__ __launch_bounds__(256) void k_scan(const int* __restrict__ counts, int* __restrict__ off) {
    int b = blockIdx.x;
    const int* c = counts + b*NN;
    int* o = off + b*NN;
    __shared__ int part[256];
    __shared__ int partScan[256];
    int tid = threadIdx.x;
    int base = tid*16;
    int s = 0;
    for (int i = 0; i < 16; ++i) s += c[base+i];
    part[tid] = s;
    __syncthreads();
    if (tid == 0) { int a = 0; for (int i = 0; i < 256; ++i) { partScan[i] = a; a += part[i]; } }
    __syncthreads();
    int a = partScan[tid];
    for (int i = 0; i < 16; ++i) { o[base+i] = a; a += c[base+i]; }
}

__global__ void k_fill(const int* __restrict__ knn, const int* __restrict__ off,
                       int* __restrict__ cursor, int* __restrict__ slots) {
    int i = blockIdx.x*blockDim.x + threadIdx.x;
    if (i >= BB*NN*KNB) return;
    int b = i / (NN*KNB);
    int nk = i % (NN*KNB);
    int m = knn[i];
    int p = atomicAdd(&cursor[b*NN + m], 1);
    slots[(size_t)b*NN*KNB + off[b*NN + m] + p] = nk;
}

// Segment sum in scatter order (n,k ascending), sequential fp32 unfused adds.
__global__ void k_segsum(const int* __restrict__ off, const int* __restrict__ counts,
                         int* __restrict__ slots, const float* __restrict__ attn,
                         float* __restrict__ score) {
    int i = blockIdx.x*blockDim.x + threadIdx.x;
    if (i >= BB*NN) return;
    int b = i / NN;
    int o = off[i], cnt = counts[i];
    int* s = slots + (size_t)b*NN*KNB + o;
    for (int a = 1; a < cnt; ++a) {
        int key = s[a]; int j = a-1;
        while (j >= 0 && s[j] > key) { s[j+1] = s[j]; --j; }
        s[j+1] = key;
    }
    const float* ab = attn + (size_t)b*NN*KNB;
    float acc = 0.f;
    for (int a = 0; a < cnt; ++a) acc = __fadd_rn(acc, ab[s[a]]);
    score[i] = acc;
}

// Full bitonic sort of (fp32 val, idx); DESC: val desc/idx asc, ASC: val asc/idx asc.
template<bool DESC>
__global__ __launch_bounds__(256) void k_topsort(const float* __restrict__ val,
                                                 float* __restrict__ idx_out,
                                                 int* __restrict__ sel_out, int outCount) {
    int b = blockIdx.x;
    __shared__ float v[NN];
    __shared__ int  id[NN];
    for (int i = threadIdx.x; i < NN; i += 256) { v[i] = val[b*NN + i]; id[i] = i; }
    __syncthreads();
    for (int k = 2; k <= NN; k <<= 1) {
        for (int j = k >> 1; j > 0; j >>= 1) {
            for (int i = threadIdx.x; i < NN; i += 256) {
                int ixj = i ^ j;
                if (ixj > i) {
                    float va = v[i], vb = v[ixj];
                    int ia = id[i], ib = id[ixj];
                    bool before = DESC ? (va > vb || (va == vb && ia < ib))
                                       : (va < vb || (va == vb && ia < ib));
                    bool up = ((i & k) == 0);
                    if (up ? !before : before) {
                        v[i] = vb; v[ixj] = va; id[i] = ib; id[ixj] = ia;
                    }
                }
            }
            __syncthreads();
        }
    }
    for (int i = threadIdx.x; i < outCount; i += 256) {
        idx_out[b*outCount + i] = (float)id[i];
        sel_out[b*outCount + i] = id[i];
    }
}

// out[b,c,j] = sum_k attn[nsel,k]*(vxT[m_k,c]-vxT[nsel,c])
__global__ __launch_bounds__(CC) void k_gather(const float* __restrict__ vxT,
                                               const float* __restrict__ attn,
                                               const int* __restrict__ knn,
                                               const int* __restrict__ sel_ds,
                                               const int* __restrict__ sel_dr,
                                               float* __restrict__ out) {
    int blk = blockIdx.x;
    int c = threadIdx.x;
    bool dropped = false;
    if (blk >= BB*MSEL) { dropped = true; blk -= BB*MSEL; }
    int b = blk / MSEL, jj = blk % MSEL;
    int nsel = dropped ? sel_dr[b*NDROP + jj] : sel_ds[b*MSEL + jj];
    const float* arow = attn + ((size_t)b*NN + nsel)*KNB;
    const int*   krow = knn  + ((size_t)b*NN + nsel)*KNB;
    const float* vb   = vxT  + (size_t)b*NN*CC;
    __shared__ float a_s[KNB];
    __shared__ int   m_s[KNB];
    __shared__ float vn[CC];
    if (c < KNB) { a_s[c] = arow[c]; m_s[c] = krow[c]; }
    vn[c] = vb[(size_t)nsel*CC + c];
    __syncthreads();
    float acc = 0.f;
    for (int k = 0; k < KNB; ++k)
        acc += a_s[k] * (vb[(size_t)m_s[k]*CC + c] - vn[c]);
    float* obase = out + (dropped ? OUT_XDR : OUT_XDS);
    obase[((size_t)b*CC + c)*MSEL + jj] = acc;
}

extern "C" void kernel_launch(void* const* d_in, const int* in_sizes, int n_in,
                              void* d_out, int out_size, void* d_ws, size_t ws_size,
                              hipStream_t stream) {
    const float* x  = (const float*)d_in[0];
    const float* Wq = (const float*)d_in[1];
    const float* Wk = (const float*)d_in[2];
    const float* Wv = (const float*)d_in[3];
    float* out = (float*)d_out;
    char* ws = (char*)d_ws;

    float*  WTq   = (float*) (ws + WS_WTQ);
    float*  WTv   = (float*) (ws + WS_WTV);
    double* sqD   = (double*)(ws + WS_SQ);
    float*  sqF   = (float*) (ws + WS_SQF);
    float*  qT    = (float*) (ws + WS_QT);
    float*  vxT   = (float*) (ws + WS_VXT);
    int*    knn   = (int*)   (ws + WS_KNN);
    float*  attnF = (float*) (ws + WS_ATTNF);
    float*  stdF  = (float*) (ws + WS_STD);
    float*  score = (float*) (ws + WS_SCORE);
    int*    counts= (int*)   (ws + WS_COUNTS);
    int*    cursor= (int*)   (ws + WS_CURSOR);
    int*    off   = (int*)   (ws + WS_OFF);
    int*    slots = (int*)   (ws + WS_SLOTS);
    int*    selds = (int*)   (ws + WS_SELDS);
    int*    seldr = (int*)   (ws + WS_SELDR);

    hipLaunchKernelGGL(k_transposeW, dim3(CC), dim3(CC), 0, stream, Wq, Wv, WTq, WTv);
    hipLaunchKernelGGL(k_sq, dim3((BB*NN + 255)/256), dim3(256), 0, stream, x, sqD, sqF);
    hipLaunchKernelGGL(k_proj, dim3(BB*NN), dim3(CC), 0, stream, x, WTq, WTv, qT, vxT);
    hipLaunchKernelGGL(k_knn, dim3(BB*NN), dim3(256), 0, stream, x, sqD, sqF, knn);
    hipLaunchKernelGGL(k_energy, dim3(BB*NN), dim3(CC), 0, stream, x, qT, Wk, knn, attnF, stdF);

    hipMemsetAsync(counts, 0, BB*NN*4, stream);
    hipMemsetAsync(cursor, 0, BB*NN*4, stream);
    hipLaunchKernelGGL(k_count, dim3((BB*NN*KNB + 255)/256), dim3(256), 0, stream, knn, counts);
    hipLaunchKernelGGL(k_scan, dim3(BB), dim3(256), 0, stream, counts, off);
    hipLaunchKernelGGL(k_fill, dim3((BB*NN*KNB + 255)/256), dim3(256), 0, stream, knn, off, cursor, slots);
    hipLaunchKernelGGL(k_segsum, dim3((BB*NN + 255)/256), dim3(256), 0, stream, off, counts, slots, attnF, score);

    hipLaunchKernelGGL((k_topsort<true>),  dim3(BB), dim3(256), 0, stream, score, out + OUT_IDX,  selds, MSEL);
    hipLaunchKernelGGL((k_topsort<false>), dim3(BB), dim3(256), 0, stream, stdF,  out + OUT_IDXD, seldr, NDROP);

    hipLaunchKernelGGL(k_gather, dim3(BB*(MSEL + NDROP)), dim3(CC), 0, stream, vxT, attnF, knn, selds, seldr, out);
}

// Round 9
// 2483.092 us; speedup vs baseline: 17.4969x; 17.4969x over previous
//
#include <hip/hip_runtime.h>
#include <float.h>
#include <math.h>

#define BB 2
#define CC 128
#define NN 4096
#define KNB 32
#define KSEL 34
#define MSEL 2048
#define NDROP 2048
#define CHUNKSZ 1024
#define NCHUNK 128   // NN*KNB / CHUNKSZ per batch

// ---------------- workspace layout (bytes) ----------------
#define WS_WTQ    0
#define WS_WTV    (WS_WTQ + CC*CC*4)
#define WS_SQ     (WS_WTV + CC*CC*4)                 // double[BB*NN]
#define WS_SQF    (WS_SQ + BB*NN*8)                  // float[BB*NN]
#define WS_QT     (WS_SQF + BB*NN*4)                 // float[BB*NN*CC]
#define WS_VXT    (WS_QT  + BB*NN*CC*4)              // float[BB*NN*CC]
#define WS_KNN    (WS_VXT + BB*NN*CC*4)              // int
#define WS_ATTNF  (WS_KNN + BB*NN*KNB*4)             // float
#define WS_STD    (WS_ATTNF + BB*NN*KNB*4)           // float[BB*NN]
#define WS_SCORE  (WS_STD + BB*NN*4)                 // float[BB*NN]
#define WS_COUNTS (WS_SCORE + BB*NN*4)
#define WS_OFF    (WS_COUNTS + BB*NN*4)
#define WS_SLOTS  (WS_OFF + BB*NN*4)
#define WS_CHUNK  (WS_SLOTS + BB*NN*KNB*4)           // int[BB][NCHUNK][NN] = 4MB
#define WS_SELDS  (WS_CHUNK + BB*NCHUNK*NN*4)
#define WS_SELDR  (WS_SELDS + BB*MSEL*4)
#define WS_END    (WS_SELDR + BB*NDROP*4)

// ---------------- output layout (floats) ----------------
#define OUT_XDS  0
#define OUT_IDX  (BB*CC*MSEL)
#define OUT_XDR  (OUT_IDX + BB*MSEL)
#define OUT_IDXD (OUT_XDR + BB*CC*NDROP)

// XLA:CPU-style sequential reduction over 32 contiguous fp32 (unfused adds).
__device__ __forceinline__ float seq32(const float* a) {
    float acc = a[0];
    #pragma unroll
    for (int i = 1; i < 32; ++i) acc = __fadd_rn(acc, a[i]);
    return acc;
}

// XLA lowers exp -> libm expf (nearly correctly rounded): emulate via double.
__device__ __forceinline__ float xla_expf(float x) {
    return (float)exp((double)x);
}

__global__ void k_transposeW(const float* __restrict__ Wq, const float* __restrict__ Wv,
                             float* __restrict__ WTq, float* __restrict__ WTv) {
    int c = blockIdx.x, o = threadIdx.x;
    WTq[c*CC + o] = Wq[o*CC + c];
    WTv[c*CC + o] = Wv[o*CC + c];
}

// sqD: fp64 (robust candidate selection). sqF: fp32 sequential (ref-emu).
__global__ void k_sq(const float* __restrict__ x, double* __restrict__ sqD,
                     float* __restrict__ sqF) {
    int i = blockIdx.x*blockDim.x + threadIdx.x;
    if (i >= BB*NN) return;
    int b = i / NN, n = i % NN;
    const float* xb = x + (size_t)b*CC*NN;
    double s = 0.0;
    float sf = 0.f;
    for (int c = 0; c < CC; ++c) {
        float v = xb[(size_t)c*NN + n];
        s += (double)v * (double)v;
        sf = __fadd_rn(sf, __fmul_rn(v, v));
    }
    sqD[i] = s; sqF[i] = sf;
}

// q: XLA-emu (sequential over c, FMA). v: plain fp32 (lenient outputs).
__global__ __launch_bounds__(CC) void k_proj(const float* __restrict__ x,
                                             const float* __restrict__ WTq,
                                             const float* __restrict__ WTv,
                                             float* __restrict__ qT,
                                             float* __restrict__ vxT) {
    int bn = blockIdx.x;
    int b = bn / NN, n = bn % NN;
    int o = threadIdx.x;
    __shared__ float xs[CC];
    xs[o] = x[(size_t)b*CC*NN + (size_t)o*NN + n];
    __syncthreads();
    float aq = 0.f, av = 0.f;
    for (int c = 0; c < CC; ++c) {
        float xv = xs[c];
        aq = fmaf(WTq[c*CC + o], xv, aq);
        av = fmaf(WTv[c*CC + o], xv, av);
    }
    size_t base = (size_t)bn*CC + o;
    qT[base] = aq; vxT[base] = av;
}

// KNN: fp64 selection of top-KSEL, then re-rank by fp32 dist with stable
// index tie-break (matches ref fp32 ordering at quantization ties).
__global__ __launch_bounds__(256) void k_knn(const float* __restrict__ x,
                                             const double* __restrict__ sqD,
                                             const float* __restrict__ sqF,
                                             int* __restrict__ knn) {
    __shared__ double xs[CC];
    __shared__ double dist[NN];
    __shared__ double rv[4];
    __shared__ int   ri[4];
    __shared__ int   selIdx[KSEL];
    __shared__ float selDist[KSEL];
    int b = blockIdx.x / NN;
    int n = blockIdx.x % NN;
    int tid = threadIdx.x;
    const float*  xb  = x   + (size_t)b*CC*NN;
    const double* sqb = sqD + b*NN;
    const float*  sqf = sqF + b*NN;
    for (int c = tid; c < CC; c += 256) xs[c] = (double)xb[(size_t)c*NN + n];
    __syncthreads();
    double sqn = sqb[n];
    for (int m = tid; m < NN; m += 256) {
        double acc = 0.0;
        for (int c = 0; c < CC; ++c) acc += xs[c] * (double)xb[(size_t)c*NN + m];
        dist[m] = (sqn + sqb[m]) - 2.0*acc;
    }
    __syncthreads();
    int wid = tid >> 6, lane = tid & 63;
    for (int kk = 0; kk < KSEL; ++kk) {
        double bv = DBL_MAX; int bi = NN;
        for (int m = tid; m < NN; m += 256) {
            double v = dist[m];
            if (v < bv || (v == bv && m < bi)) { bv = v; bi = m; }
        }
        for (int off = 32; off > 0; off >>= 1) {
            double ov = __shfl_down(bv, off);
            int    oi = __shfl_down(bi, off);
            if (ov < bv || (ov == bv && oi < bi)) { bv = ov; bi = oi; }
        }
        if (lane == 0) { rv[wid] = bv; ri[wid] = bi; }
        __syncthreads();
        if (tid == 0) {
            double fv = rv[0]; int fi = ri[0];
            for (int w = 1; w < 4; ++w)
                if (rv[w] < fv || (rv[w] == fv && ri[w] < fi)) { fv = rv[w]; fi = ri[w]; }
            selIdx[kk] = fi;
            dist[fi] = DBL_MAX;
        }
        __syncthreads();
    }
    if (tid < KSEL) {
        int m = selIdx[tid];
        float acc = 0.f;
        for (int c = 0; c < CC; ++c)
            acc = __fadd_rn(acc, __fmul_rn((float)xs[c], xb[(size_t)c*NN + m]));
        selDist[tid] = __fsub_rn(__fadd_rn(sqf[n], sqf[m]), __fmul_rn(2.0f, acc));
    }
    __syncthreads();
    if (tid == 0) {
        for (int a = 1; a < KSEL; ++a) {
            float dv = selDist[a]; int iv = selIdx[a]; int j = a-1;
            while (j >= 0 && (selDist[j] > dv || (selDist[j] == dv && selIdx[j] > iv))) {
                selDist[j+1] = selDist[j]; selIdx[j+1] = selIdx[j]; --j;
            }
            selDist[j+1] = dv; selIdx[j+1] = iv;
        }
        for (int kk = 0; kk < KNB; ++kk)
            knn[(size_t)blockIdx.x*KNB + kk] = selIdx[kk];
    }
}

// XLA-emu of k = Wk @ (x_m - x_n), energy = q . k (sequential FMA), then
// softmax + std with SEQUENTIAL 32-length reductions (XLA reduce order).
__global__ __launch_bounds__(CC) void k_energy(const float* __restrict__ x,
                                               const float* __restrict__ qT,
                                               const float* __restrict__ Wk,
                                               const int* __restrict__ knn,
                                               float* __restrict__ attnF,
                                               float* __restrict__ stdF) {
    int bn = blockIdx.x;
    int b = bn / NN, n = bn % NN;
    int o = threadIdx.x;
    __shared__ float xn[CC];
    __shared__ float qs[CC];
    __shared__ int   mIdx[KNB];
    __shared__ float nb[KNB][CC];
    __shared__ float kmat[KNB][CC];
    __shared__ float es[KNB];
    const float* xb = x + (size_t)b*CC*NN;
    xn[o] = xb[(size_t)o*NN + n];
    qs[o] = qT[(size_t)bn*CC + o];
    if (o < KNB) mIdx[o] = knn[(size_t)bn*KNB + o];
    __syncthreads();
    #pragma unroll
    for (int kk = 0; kk < KNB; ++kk)
        nb[kk][o] = __fsub_rn(xb[(size_t)o*NN + mIdx[kk]], xn[o]);
    __syncthreads();
    float acc[KNB];
    #pragma unroll
    for (int kk = 0; kk < KNB; ++kk) acc[kk] = 0.f;
    const float* wrow = Wk + (size_t)o*CC;
    for (int c = 0; c < CC; ++c) {
        float w = wrow[c];
        #pragma unroll
        for (int kk = 0; kk < KNB; ++kk)
            acc[kk] = fmaf(w, nb[kk][c], acc[kk]);
    }
    #pragma unroll
    for (int kk = 0; kk < KNB; ++kk) kmat[kk][o] = acc[kk];
    __syncthreads();
    if (o < KNB) {
        float e = 0.f;
        for (int d = 0; d < CC; ++d)
            e = fmaf(qs[d], kmat[o][d], e);
        es[o] = __fdiv_rn(e, __fsqrt_rn(128.0f));
    }
    __syncthreads();
    if (o == 0) {
        float mx = es[0];
        #pragma unroll
        for (int kk = 1; kk < KNB; ++kk) mx = fmaxf(mx, es[kk]);
        float p[KNB], a[KNB], d2[KNB];
        #pragma unroll
        for (int kk = 0; kk < KNB; ++kk)
            p[kk] = xla_expf(__fsub_rn(es[kk], mx));
        float s = seq32(p);
        #pragma unroll
        for (int kk = 0; kk < KNB; ++kk) {
            a[kk] = __fdiv_rn(p[kk], s);
            attnF[(size_t)bn*KNB + kk] = a[kk];
        }
        float mean = __fdiv_rn(seq32(a), 32.0f);
        #pragma unroll
        for (int kk = 0; kk < KNB; ++kk) {
            float dd = __fsub_rn(a[kk], mean);
            d2[kk] = __fmul_rn(dd, dd);
        }
        float var = __fdiv_rn(seq32(d2), 32.0f);
        stdF[bn] = __fsqrt_rn(var);
    }
}

__global__ void k_count(const int* __restrict__ knn, int* __restrict__ counts) {
    int i = blockIdx.x*blockDim.x + threadIdx.x;
    if (i >= BB*NN*KNB) return;
    int b = i / (NN*KNB);
    atomicAdd(&counts[b*NN + knn[i]], 1);
}

__global__ __launch_bounds__(256) void k_scan(const int* __restrict__ counts, int* __restrict__ off) {
    int b = blockIdx.x;
    const int* c = counts + b*NN;
    int* o = off + b*NN;
    __shared__ int part[256];
    __shared__ int partScan[256];
    int tid = threadIdx.x;
    int base = tid*16;
    int s = 0;
    for (int i = 0; i < 16; ++i) s += c[base+i];
    part[tid] = s;
    __syncthreads();
    if (tid == 0) { int a = 0; for (int i = 0; i < 256; ++i) { partScan[i] = a; a += part[i]; } }
    __syncthreads();
    int a = partScan[tid];
    for (int i = 0; i < 16; ++i) { o[base+i] = a; a += c[base+i]; }
}

// Per-chunk histogram over segment ids (deterministic; LDS atomics).
__global__ __launch_bounds__(256) void k_chunkcount(const int* __restrict__ knn,
                                                    int* __restrict__ chunkCnt) {
    __shared__ int hist[NN];
    int b = blockIdx.x / NCHUNK, p = blockIdx.x % NCHUNK;
    int tid = threadIdx.x;
    for (int i = tid; i < NN; i += 256) hist[i] = 0;
    __syncthreads();
    const int* kb = knn + (size_t)b*NN*KNB + (size_t)p*CHUNKSZ;
    for (int i = tid; i < CHUNKSZ; i += 256)
        atomicAdd(&hist[kb[i]], 1);
    __syncthreads();
    int* row = chunkCnt + ((size_t)b*NCHUNK + p)*NN;
    for (int i = tid; i < NN; i += 256) row[i] = hist[i];
}

// Per (b,m): exclusive scan of chunkCnt over chunks (in place).
__global__ __launch_bounds__(256) void k_chunkscan(int* __restrict__ chunkCnt) {
    int i = blockIdx.x*blockDim.x + threadIdx.x;
    if (i >= BB*NN) return;
    int b = i / NN, m = i % NN;
    int running = 0;
    for (int p = 0; p < NCHUNK; ++p) {
        size_t idx = ((size_t)b*NCHUNK + p)*NN + m;
        int t = chunkCnt[idx];
        chunkCnt[idx] = running;
        running += t;
    }
}

// Stable fill: local rank within chunk (#earlier same-m elements) + chunk base.
// slots content becomes deterministic ascending-(n,k) order per segment.
__global__ __launch_bounds__(256) void k_fill2(const int* __restrict__ knn,
                                               const int* __restrict__ off,
                                               const int* __restrict__ chunkCnt,
                                               int* __restrict__ slots) {
    __shared__ int mv[CHUNKSZ];
    int b = blockIdx.x / NCHUNK, p = blockIdx.x % NCHUNK;
    int tid = threadIdx.x;
    const int* kb = knn + (size_t)b*NN*KNB + (size_t)p*CHUNKSZ;
    for (int i = tid; i < CHUNKSZ; i += 256) mv[i] = kb[i];
    __syncthreads();
    const int* cbase = chunkCnt + ((size_t)b*NCHUNK + p)*NN;
    const int* ob    = off + b*NN;
    int* sb = slots + (size_t)b*NN*KNB;
    for (int i = tid; i < CHUNKSZ; i += 256) {
        int m = mv[i];
        int rank = 0;
        for (int j = 0; j < i; ++j) rank += (mv[j] == m);
        sb[ob[m] + cbase[m] + rank] = p*CHUNKSZ + i;
    }
}

// Segment sum in ascending (n,k) order, sequential fp32 unfused adds. No sort.
__global__ void k_segsum(const int* __restrict__ off, const int* __restrict__ counts,
                         const int* __restrict__ slots, const float* __restrict__ attn,
                         float* __restrict__ score) {
    int i = blockIdx.x*blockDim.x + threadIdx.x;
    if (i >= BB*NN) return;
    int b = i / NN;
    int o = off[i], cnt = counts[i];
    const int* s = slots + (size_t)b*NN*KNB + o;
    const float* ab = attn + (size_t)b*NN*KNB;
    float acc = 0.f;
    for (int a = 0; a < cnt; ++a) acc = __fadd_rn(acc, ab[s[a]]);
    score[i] = acc;
}

// Full bitonic sort of (fp32 val, idx); DESC: val desc/idx asc, ASC: val asc/idx asc.
template<bool DESC>
__global__ __launch_bounds__(256) void k_topsort(const float* __restrict__ val,
                                                 float* __restrict__ idx_out,
                                                 int* __restrict__ sel_out, int outCount) {
    int b = blockIdx.x;
    __shared__ float v[NN];
    __shared__ int  id[NN];
    for (int i = threadIdx.x; i < NN; i += 256) { v[i] = val[b*NN + i]; id[i] = i; }
    __syncthreads();
    for (int k = 2; k <= NN; k <<= 1) {
        for (int j = k >> 1; j > 0; j >>= 1) {
            for (int i = threadIdx.x; i < NN; i += 256) {
                int ixj = i ^ j;
                if (ixj > i) {
                    float va = v[i], vb = v[ixj];
                    int ia = id[i], ib = id[ixj];
                    bool before = DESC ? (va > vb || (va == vb && ia < ib))
                                       : (va < vb || (va == vb && ia < ib));
                    bool up = ((i & k) == 0);
                    if (up ? !before : before) {
                        v[i] = vb; v[ixj] = va; id[i] = ib; id[ixj] = ia;
                    }
                }
            }
            __syncthreads();
        }
    }
    for (int i = threadIdx.x; i < outCount; i += 256) {
        idx_out[b*outCount + i] = (float)id[i];
        sel_out[b*outCount + i] = id[i];
    }
}

// out[b,c,j] = sum_k attn[nsel,k]*(vxT[m_k,c]-vxT[nsel,c])
__global__ __launch_bounds__(CC) void k_gather(const float* __restrict__ vxT,
                                               const float* __restrict__ attn,
                                               const int* __restrict__ knn,
                                               const int* __restrict__ sel_ds,
                                               const int* __restrict__ sel_dr,
                                               float* __restrict__ out) {
    int blk = blockIdx.x;
    int c = threadIdx.x;
    bool dropped = false;
    if (blk >= BB*MSEL) { dropped = true; blk -= BB*MSEL; }
    int b = blk / MSEL, jj = blk % MSEL;
    int nsel = dropped ? sel_dr[b*NDROP + jj] : sel_ds[b*MSEL + jj];
    const float* arow = attn + ((size_t)b*NN + nsel)*KNB;
    const int*   krow = knn  + ((size_t)b*NN + nsel)*KNB;
    const float* vb   = vxT  + (size_t)b*NN*CC;
    __shared__ float a_s[KNB];
    __shared__ int   m_s[KNB];
    __shared__ float vn[CC];
    if (c < KNB) { a_s[c] = arow[c]; m_s[c] = krow[c]; }
    vn[c] = vb[(size_t)nsel*CC + c];
    __syncthreads();
    float acc = 0.f;
    for (int k = 0; k < KNB; ++k)
        acc += a_s[k] * (vb[(size_t)m_s[k]*CC + c] - vn[c]);
    float* obase = out + (dropped ? OUT_XDR : OUT_XDS);
    obase[((size_t)b*CC + c)*MSEL + jj] = acc;
}

extern "C" void kernel_launch(void* const* d_in, const int* in_sizes, int n_in,
                              void* d_out, int out_size, void* d_ws, size_t ws_size,
                              hipStream_t stream) {
    const float* x  = (const float*)d_in[0];
    const float* Wq = (const float*)d_in[1];
    const float* Wk = (const float*)d_in[2];
    const float* Wv = (const float*)d_in[3];
    float* out = (float*)d_out;
    char* ws = (char*)d_ws;

    float*  WTq    = (float*) (ws + WS_WTQ);
    float*  WTv    = (float*) (ws + WS_WTV);
    double* sqD    = (double*)(ws + WS_SQ);
    float*  sqF    = (float*) (ws + WS_SQF);
    float*  qT     = (float*) (ws + WS_QT);
    float*  vxT    = (float*) (ws + WS_VXT);
    int*    knn    = (int*)   (ws + WS_KNN);
    float*  attnF  = (float*) (ws + WS_ATTNF);
    float*  stdF   = (float*) (ws + WS_STD);
    float*  score  = (float*) (ws + WS_SCORE);
    int*    counts = (int*)   (ws + WS_COUNTS);
    int*    off    = (int*)   (ws + WS_OFF);
    int*    slots  = (int*)   (ws + WS_SLOTS);
    int*    chunkC = (int*)   (ws + WS_CHUNK);
    int*    selds  = (int*)   (ws + WS_SELDS);
    int*    seldr  = (int*)   (ws + WS_SELDR);

    hipLaunchKernelGGL(k_transposeW, dim3(CC), dim3(CC), 0, stream, Wq, Wv, WTq, WTv);
    hipLaunchKernelGGL(k_sq, dim3((BB*NN + 255)/256), dim3(256), 0, stream, x, sqD, sqF);
    hipLaunchKernelGGL(k_proj, dim3(BB*NN), dim3(CC), 0, stream, x, WTq, WTv, qT, vxT);
    hipLaunchKernelGGL(k_knn, dim3(BB*NN), dim3(256), 0, stream, x, sqD, sqF, knn);
    hipLaunchKernelGGL(k_energy, dim3(BB*NN), dim3(CC), 0, stream, x, qT, Wk, knn, attnF, stdF);

    hipMemsetAsync(counts, 0, BB*NN*4, stream);
    hipLaunchKernelGGL(k_count, dim3((BB*NN*KNB + 255)/256), dim3(256), 0, stream, knn, counts);
    hipLaunchKernelGGL(k_scan, dim3(BB), dim3(256), 0, stream, counts, off);
    hipLaunchKernelGGL(k_chunkcount, dim3(BB*NCHUNK), dim3(256), 0, stream, knn, chunkC);
    hipLaunchKernelGGL(k_chunkscan, dim3((BB*NN + 255)/256), dim3(256), 0, stream, chunkC);
    hipLaunchKernelGGL(k_fill2, dim3(BB*NCHUNK), dim3(256), 0, stream, knn, off, chunkC, slots);
    hipLaunchKernelGGL(k_segsum, dim3((BB*NN + 255)/256), dim3(256), 0, stream, off, counts, slots, attnF, score);

    hipLaunchKernelGGL((k_topsort<true>),  dim3(BB), dim3(256), 0, stream, score, out + OUT_IDX,  selds, MSEL);
    hipLaunchKernelGGL((k_topsort<false>), dim3(BB), dim3(256), 0, stream, stdF,  out + OUT_IDXD, seldr, NDROP);

    hipLaunchKernelGGL(k_gather, dim3(BB*(MSEL + NDROP)), dim3(CC), 0, stream, vxT, attnF, knn, selds, seldr, out);
}

// Round 10
// 1952.406 us; speedup vs baseline: 22.2527x; 1.2718x over previous
//
#include <hip/hip_runtime.h>
#include <float.h>
#include <math.h>

#define BB 2
#define CC 128
#define NN 4096
#define KNB 32
#define KSEL 40
#define GN 4
#define MSEL 2048
#define NDROP 2048
#define CHUNKSZ 1024
#define NCHUNK 128   // NN*KNB / CHUNKSZ per batch

// ---------------- workspace layout (bytes) ----------------
#define WS_WTQ    0
#define WS_WTV    (WS_WTQ + CC*CC*4)
#define WS_SQF    (WS_WTV + CC*CC*4)                 // float[BB*NN]
#define WS_XT     (WS_SQF + BB*NN*4)                 // float[BB*NN*CC] (x transposed)
#define WS_QT     (WS_XT  + BB*NN*CC*4)              // float[BB*NN*CC]
#define WS_VXT    (WS_QT  + BB*NN*CC*4)              // float[BB*NN*CC]
#define WS_KNN    (WS_VXT + BB*NN*CC*4)              // int
#define WS_ATTNF  (WS_KNN + BB*NN*KNB*4)             // float
#define WS_STD    (WS_ATTNF + BB*NN*KNB*4)           // float[BB*NN]
#define WS_SCORE  (WS_STD + BB*NN*4)                 // float[BB*NN]
#define WS_COUNTS (WS_SCORE + BB*NN*4)
#define WS_OFF    (WS_COUNTS + BB*NN*4)
#define WS_SLOTS  (WS_OFF + BB*NN*4)
#define WS_CHUNK  (WS_SLOTS + BB*NN*KNB*4)           // int[BB][NCHUNK][NN] = 4MB
#define WS_SELDS  (WS_CHUNK + BB*NCHUNK*NN*4)
#define WS_SELDR  (WS_SELDS + BB*MSEL*4)
#define WS_END    (WS_SELDR + BB*NDROP*4)

// ---------------- output layout (floats) ----------------
#define OUT_XDS  0
#define OUT_IDX  (BB*CC*MSEL)
#define OUT_XDR  (OUT_IDX + BB*MSEL)
#define OUT_IDXD (OUT_XDR + BB*CC*NDROP)

// XLA:CPU-style sequential reduction over 32 contiguous fp32 (unfused adds).
__device__ __forceinline__ float seq32(const float* a) {
    float acc = a[0];
    #pragma unroll
    for (int i = 1; i < 32; ++i) acc = __fadd_rn(acc, a[i]);
    return acc;
}

// XLA lowers exp -> libm expf (nearly correctly rounded): emulate via double.
__device__ __forceinline__ float xla_expf(float x) {
    return (float)exp((double)x);
}

__global__ void k_transposeW(const float* __restrict__ Wq, const float* __restrict__ Wv,
                             float* __restrict__ WTq, float* __restrict__ WTv) {
    int c = blockIdx.x, o = threadIdx.x;
    WTq[c*CC + o] = Wq[o*CC + c];
    WTv[c*CC + o] = Wv[o*CC + c];
}

// x [b][c][n] -> xT [b][n][c] (LDS tile transpose; values untouched)
__global__ __launch_bounds__(256) void k_transposeX(const float* __restrict__ x,
                                                    float* __restrict__ xT) {
    __shared__ float t[32][33];
    int b  = blockIdx.z;
    int n0 = blockIdx.x * 32;
    int c0 = blockIdx.y * 32;
    int tx = threadIdx.x & 31, ty = threadIdx.x >> 5;  // 32 x 8
    const float* xb = x + (size_t)b*CC*NN;
    for (int r = ty; r < 32; r += 8)
        t[r][tx] = xb[(size_t)(c0+r)*NN + n0 + tx];
    __syncthreads();
    float* xo = xT + (size_t)b*NN*CC;
    for (int r = ty; r < 32; r += 8)
        xo[(size_t)(n0+r)*CC + c0 + tx] = t[tx][r];
}

// sqF: fp32 sequential over c (exact ref-emu; reads xT row contiguously).
__global__ void k_sq(const float* __restrict__ xT, float* __restrict__ sqF) {
    int i = blockIdx.x*blockDim.x + threadIdx.x;
    if (i >= BB*NN) return;
    const float* row = xT + (size_t)i*CC;
    float sf = 0.f;
    for (int c = 0; c < CC; ++c)
        sf = __fadd_rn(sf, __fmul_rn(row[c], row[c]));
    sqF[i] = sf;
}

// q: XLA-emu (sequential over c, FMA). v: plain fp32 (lenient outputs).
__global__ __launch_bounds__(CC) void k_proj(const float* __restrict__ xT,
                                             const float* __restrict__ WTq,
                                             const float* __restrict__ WTv,
                                             float* __restrict__ qT,
                                             float* __restrict__ vxT) {
    int bn = blockIdx.x;
    int o = threadIdx.x;
    __shared__ float xs[CC];
    xs[o] = xT[(size_t)bn*CC + o];
    __syncthreads();
    float aq = 0.f, av = 0.f;
    for (int c = 0; c < CC; ++c) {
        float xv = xs[c];
        aq = fmaf(WTq[c*CC + o], xv, aq);
        av = fmaf(WTv[c*CC + o], xv, av);
    }
    size_t base = (size_t)bn*CC + o;
    qT[base] = aq; vxT[base] = av;
}

// KNN: fast fp32 gram selects top-KSEL superset (cached-local-min argmin per wave),
// then re-rank by EXACT ref-emulated fp32 dist (frozen arithmetic) -> top-32.
__global__ __launch_bounds__(256) void k_knn(const float* __restrict__ xT,
                                             const float* __restrict__ sqF,
                                             int* __restrict__ knn) {
    __shared__ float xs[GN][CC];
    __shared__ float dist[GN][NN];
    __shared__ int   candIdx[GN][KSEL];
    __shared__ float candDist[GN][KSEL];
    int blk = blockIdx.x;
    int b  = blk / (NN/GN);
    int n0 = (blk % (NN/GN)) * GN;
    int tid = threadIdx.x;
    const float* xbT = xT  + (size_t)b*NN*CC;
    const float* sqf = sqF + b*NN;
    for (int i = tid; i < GN*CC; i += 256) {
        int g = i / CC, c = i % CC;
        xs[g][c] = xbT[(size_t)(n0+g)*CC + c];
    }
    __syncthreads();
    float sqn0 = sqf[n0+0], sqn1 = sqf[n0+1], sqn2 = sqf[n0+2], sqn3 = sqf[n0+3];
    for (int m = tid; m < NN; m += 256) {
        const float4* col = (const float4*)(xbT + (size_t)m*CC);
        const float4* q0 = (const float4*)xs[0];
        const float4* q1 = (const float4*)xs[1];
        const float4* q2 = (const float4*)xs[2];
        const float4* q3 = (const float4*)xs[3];
        float a0 = 0.f, a1 = 0.f, a2 = 0.f, a3 = 0.f;
        #pragma unroll
        for (int c4 = 0; c4 < CC/4; ++c4) {
            float4 xv = col[c4];
            float4 v0 = q0[c4], v1 = q1[c4], v2 = q2[c4], v3 = q3[c4];
            a0 += v0.x*xv.x + v0.y*xv.y + v0.z*xv.z + v0.w*xv.w;
            a1 += v1.x*xv.x + v1.y*xv.y + v1.z*xv.z + v1.w*xv.w;
            a2 += v2.x*xv.x + v2.y*xv.y + v2.z*xv.z + v2.w*xv.w;
            a3 += v3.x*xv.x + v3.y*xv.y + v3.z*xv.z + v3.w*xv.w;
        }
        float sm = sqf[m];
        dist[0][m] = sqn0 + sm - 2.f*a0;
        dist[1][m] = sqn1 + sm - 2.f*a1;
        dist[2][m] = sqn2 + sm - 2.f*a2;
        dist[3][m] = sqn3 + sm - 2.f*a3;
    }
    __syncthreads();
    // selection: wave w owns query w; lane owns m in {lane, lane+64, ...}
    int wid = tid >> 6, lane = tid & 63;
    {
        float* dr = dist[wid];
        float lv = FLT_MAX; int li = NN;
        for (int j = 0; j < NN/64; ++j) {
            int m = j*64 + lane;
            float v = dr[m];
            if (v < lv) { lv = v; li = m; }
        }
        for (int kk = 0; kk < KSEL; ++kk) {
            float bv = lv; int bi = li;
            for (int off = 32; off > 0; off >>= 1) {
                float ov = __shfl_xor(bv, off);
                int   oi = __shfl_xor(bi, off);
                if (ov < bv || (ov == bv && oi < bi)) { bv = ov; bi = oi; }
            }
            if (lane == 0) candIdx[wid][kk] = bi;
            if ((bi & 63) == lane) {
                dr[bi] = FLT_MAX;
                lv = FLT_MAX; li = NN;
                for (int j = 0; j < NN/64; ++j) {
                    int m = j*64 + lane;
                    float v = dr[m];
                    if (v < lv) { lv = v; li = m; }
                }
            }
        }
    }
    __syncthreads();
    // re-rank by ref-emulated fp32 dist (sequential unfused dot; FROZEN numerics)
    int g = tid >> 6, j = tid & 63;
    if (j < KSEL) {
        int m = candIdx[g][j];
        const float* colm = xbT + (size_t)m*CC;
        float acc = 0.f;
        for (int c = 0; c < CC; ++c)
            acc = __fadd_rn(acc, __fmul_rn(xs[g][c], colm[c]));
        candDist[g][j] = __fsub_rn(__fadd_rn(sqf[n0+g], sqf[m]), __fmul_rn(2.0f, acc));
    }
    __syncthreads();
    if (j < KSEL) {
        float dme = candDist[g][j]; int ime = candIdx[g][j];
        int rank = 0;
        for (int t = 0; t < KSEL; ++t) {
            float dt = candDist[g][t]; int it = candIdx[g][t];
            if (dt < dme || (dt == dme && it < ime)) ++rank;
        }
        if (rank < KNB)
            knn[((size_t)b*NN + n0 + g)*KNB + rank] = ime;
    }
}

// XLA-emu of k = Wk @ (x_m - x_n), energy = q . k (sequential FMA), then
// softmax + std with SEQUENTIAL 32-length reductions (XLA reduce order).
// Loads via xT (coalesced); arithmetic identical to the passing config.
__global__ __launch_bounds__(CC) void k_energy(const float* __restrict__ xT,
                                               const float* __restrict__ qT,
                                               const float* __restrict__ Wk,
                                               const int* __restrict__ knn,
                                               float* __restrict__ attnF,
                                               float* __restrict__ stdF) {
    int bn = blockIdx.x;
    int b = bn / NN;
    int o = threadIdx.x;
    __shared__ float xn[CC];
    __shared__ float qs[CC];
    __shared__ int   mIdx[KNB];
    __shared__ float nb[KNB][CC];
    __shared__ float kmat[KNB][CC];
    __shared__ float es[KNB];
    const float* xbT = xT + (size_t)b*NN*CC;
    xn[o] = xT[(size_t)bn*CC + o];
    qs[o] = qT[(size_t)bn*CC + o];
    if (o < KNB) mIdx[o] = knn[(size_t)bn*KNB + o];
    __syncthreads();
    #pragma unroll
    for (int kk = 0; kk < KNB; ++kk)
        nb[kk][o] = __fsub_rn(xbT[(size_t)mIdx[kk]*CC + o], xn[o]);
    __syncthreads();
    float acc[KNB];
    #pragma unroll
    for (int kk = 0; kk < KNB; ++kk) acc[kk] = 0.f;
    const float* wrow = Wk + (size_t)o*CC;
    for (int c = 0; c < CC; ++c) {
        float w = wrow[c];
        #pragma unroll
        for (int kk = 0; kk < KNB; ++kk)
            acc[kk] = fmaf(w, nb[kk][c], acc[kk]);
    }
    #pragma unroll
    for (int kk = 0; kk < KNB; ++kk) kmat[kk][o] = acc[kk];
    __syncthreads();
    if (o < KNB) {
        float e = 0.f;
        for (int d = 0; d < CC; ++d)
            e = fmaf(qs[d], kmat[o][d], e);
        es[o] = __fdiv_rn(e, __fsqrt_rn(128.0f));
    }
    __syncthreads();
    if (o == 0) {
        float mx = es[0];
        #pragma unroll
        for (int kk = 1; kk < KNB; ++kk) mx = fmaxf(mx, es[kk]);
        float p[KNB], a[KNB], d2[KNB];
        #pragma unroll
        for (int kk = 0; kk < KNB; ++kk)
            p[kk] = xla_expf(__fsub_rn(es[kk], mx));
        float s = seq32(p);
        #pragma unroll
        for (int kk = 0; kk < KNB; ++kk) {
            a[kk] = __fdiv_rn(p[kk], s);
            attnF[(size_t)bn*KNB + kk] = a[kk];
        }
        float mean = __fdiv_rn(seq32(a), 32.0f);
        #pragma unroll
        for (int kk = 0; kk < KNB; ++kk) {
            float dd = __fsub_rn(a[kk], mean);
            d2[kk] = __fmul_rn(dd, dd);
        }
        float var = __fdiv_rn(seq32(d2), 32.0f);
        stdF[bn] = __fsqrt_rn(var);
    }
}

__global__ void k_count(const int* __restrict__ knn, int* __restrict__ counts) {
    int i = blockIdx.x*blockDim.x + threadIdx.x;
    if (i >= BB*NN*KNB) return;
    int b = i / (NN*KNB);
    atomicAdd(&counts[b*NN + knn[i]], 1);
}

__global__ __launch_bounds__(256) void k_scan(const int* __restrict__ counts, int* __restrict__ off) {
    int b = blockIdx.x;
    const int* c = counts + b*NN;
    int* o = off + b*NN;
    __shared__ int part[256];
    __shared__ int partScan[256];
    int tid = threadIdx.x;
    int base = tid*16;
    int s = 0;
    for (int i = 0; i < 16; ++i) s += c[base+i];
    part[tid] = s;
    __syncthreads();
    if (tid == 0) { int a = 0; for (int i = 0; i < 256; ++i) { partScan[i] = a; a += part[i]; } }
    __syncthreads();
    int a = partScan[tid];
    for (int i = 0; i < 16; ++i) { o[base+i] = a; a += c[base+i]; }
}

// Per-chunk histogram over segment ids (deterministic; LDS atomics).
__global__ __launch_bounds__(256) void k_chunkcount(const int* __restrict__ knn,
                                                    int* __restrict__ chunkCnt) {
    __shared__ int hist[NN];
    int b = blockIdx.x / NCHUNK, p = blockIdx.x % NCHUNK;
    int tid = threadIdx.x;
    for (int i = tid; i < NN; i += 256) hist[i] = 0;
    __syncthreads();
    const int* kb = knn + (size_t)b*NN*KNB + (size_t)p*CHUNKSZ;
    for (int i = tid; i < CHUNKSZ; i += 256)
        atomicAdd(&hist[kb[i]], 1);
    __syncthreads();
    int* row = chunkCnt + ((size_t)b*NCHUNK + p)*NN;
    for (int i = tid; i < NN; i += 256) row[i] = hist[i];
}

// Per (b,m): exclusive scan of chunkCnt over chunks (in place).
__global__ __launch_bounds__(256) void k_chunkscan(int* __restrict__ chunkCnt) {
    int i = blockIdx.x*blockDim.x + threadIdx.x;
    if (i >= BB*NN) return;
    int b = i / NN, m = i % NN;
    int running = 0;
    for (int p = 0; p < NCHUNK; ++p) {
        size_t idx = ((size_t)b*NCHUNK + p)*NN + m;
        int t = chunkCnt[idx];
        chunkCnt[idx] = running;
        running += t;
    }
}

// Stable fill: local rank within chunk (#earlier same-m elements) + chunk base.
__global__ __launch_bounds__(256) void k_fill2(const int* __restrict__ knn,
                                               const int* __restrict__ off,
                                               const int* __restrict__ chunkCnt,
                                               int* __restrict__ slots) {
    __shared__ int mv[CHUNKSZ];
    int b = blockIdx.x / NCHUNK, p = blockIdx.x % NCHUNK;
    int tid = threadIdx.x;
    const int* kb = knn + (size_t)b*NN*KNB + (size_t)p*CHUNKSZ;
    for (int i = tid; i < CHUNKSZ; i += 256) mv[i] = kb[i];
    __syncthreads();
    const int* cbase = chunkCnt + ((size_t)b*NCHUNK + p)*NN;
    const int* ob    = off + b*NN;
    int* sb = slots + (size_t)b*NN*KNB;
    for (int i = tid; i < CHUNKSZ; i += 256) {
        int m = mv[i];
        int rank = 0;
        for (int j = 0; j < i; ++j) rank += (mv[j] == m);
        sb[ob[m] + cbase[m] + rank] = p*CHUNKSZ + i;
    }
}

// Segment sum in ascending (n,k) order, sequential fp32 unfused adds.
__global__ void k_segsum(const int* __restrict__ off, const int* __restrict__ counts,
                         const int* __restrict__ slots, const float* __restrict__ attn,
                         float* __restrict__ score) {
    int i = blockIdx.x*blockDim.x + threadIdx.x;
    if (i >= BB*NN) return;
    int b = i / NN;
    int o = off[i], cnt = counts[i];
    const int* s = slots + (size_t)b*NN*KNB + o;
    const float* ab = attn + (size_t)b*NN*KNB;
    float acc = 0.f;
    for (int a = 0; a < cnt; ++a) acc = __fadd_rn(acc, ab[s[a]]);
    score[i] = acc;
}

// Merged bitonic sorts: blocks [0,BB) sort score DESC; [BB,2BB) sort std ASC.
__global__ __launch_bounds__(256) void k_topsort2(const float* __restrict__ score,
                                                  const float* __restrict__ stdv,
                                                  float* __restrict__ out,
                                                  int* __restrict__ selds,
                                                  int* __restrict__ seldr) {
    int blk = blockIdx.x;
    bool desc = blk < BB;
    int b = desc ? blk : blk - BB;
    const float* val = (desc ? score : stdv) + b*NN;
    __shared__ float v[NN];
    __shared__ int  id[NN];
    for (int i = threadIdx.x; i < NN; i += 256) { v[i] = val[i]; id[i] = i; }
    __syncthreads();
    for (int k = 2; k <= NN; k <<= 1) {
        for (int j = k >> 1; j > 0; j >>= 1) {
            for (int i = threadIdx.x; i < NN; i += 256) {
                int ixj = i ^ j;
                if (ixj > i) {
                    float va = v[i], vb = v[ixj];
                    int ia = id[i], ib = id[ixj];
                    bool before = desc ? (va > vb || (va == vb && ia < ib))
                                       : (va < vb || (va == vb && ia < ib));
                    bool up = ((i & k) == 0);
                    if (up ? !before : before) {
                        v[i] = vb; v[ixj] = va; id[i] = ib; id[ixj] = ia;
                    }
                }
            }
            __syncthreads();
        }
    }
    float* idx_out = out + (desc ? OUT_IDX : OUT_IDXD) + b*MSEL;
    int*   sel_out = (desc ? selds : seldr) + b*MSEL;
    for (int i = threadIdx.x; i < MSEL; i += 256) {
        idx_out[i] = (float)id[i];
        sel_out[i] = id[i];
    }
}

// out[b,c,j] = sum_k attn[nsel,k]*(vxT[m_k,c]-vxT[nsel,c])
__global__ __launch_bounds__(CC) void k_gather(const float* __restrict__ vxT,
                                               const float* __restrict__ attn,
                                               const int* __restrict__ knn,
                                               const int* __restrict__ sel_ds,
                                               const int* __restrict__ sel_dr,
                                               float* __restrict__ out) {
    int blk = blockIdx.x;
    int c = threadIdx.x;
    bool dropped = false;
    if (blk >= BB*MSEL) { dropped = true; blk -= BB*MSEL; }
    int b = blk / MSEL, jj = blk % MSEL;
    int nsel = dropped ? sel_dr[b*NDROP + jj] : sel_ds[b*MSEL + jj];
    const float* arow = attn + ((size_t)b*NN + nsel)*KNB;
    const int*   krow = knn  + ((size_t)b*NN + nsel)*KNB;
    const float* vb   = vxT  + (size_t)b*NN*CC;
    __shared__ float a_s[KNB];
    __shared__ int   m_s[KNB];
    __shared__ float vn[CC];
    if (c < KNB) { a_s[c] = arow[c]; m_s[c] = krow[c]; }
    vn[c] = vb[(size_t)nsel*CC + c];
    __syncthreads();
    float acc = 0.f;
    for (int k = 0; k < KNB; ++k)
        acc += a_s[k] * (vb[(size_t)m_s[k]*CC + c] - vn[c]);
    float* obase = out + (dropped ? OUT_XDR : OUT_XDS);
    obase[((size_t)b*CC + c)*MSEL + jj] = acc;
}

extern "C" void kernel_launch(void* const* d_in, const int* in_sizes, int n_in,
                              void* d_out, int out_size, void* d_ws, size_t ws_size,
                              hipStream_t stream) {
    const float* x  = (const float*)d_in[0];
    const float* Wq = (const float*)d_in[1];
    const float* Wk = (const float*)d_in[2];
    const float* Wv = (const float*)d_in[3];
    float* out = (float*)d_out;
    char* ws = (char*)d_ws;

    float*  WTq    = (float*) (ws + WS_WTQ);
    float*  WTv    = (float*) (ws + WS_WTV);
    float*  sqF    = (float*) (ws + WS_SQF);
    float*  xT     = (float*) (ws + WS_XT);
    float*  qT     = (float*) (ws + WS_QT);
    float*  vxT    = (float*) (ws + WS_VXT);
    int*    knn    = (int*)   (ws + WS_KNN);
    float*  attnF  = (float*) (ws + WS_ATTNF);
    float*  stdF   = (float*) (ws + WS_STD);
    float*  score  = (float*) (ws + WS_SCORE);
    int*    counts = (int*)   (ws + WS_COUNTS);
    int*    off    = (int*)   (ws + WS_OFF);
    int*    slots  = (int*)   (ws + WS_SLOTS);
    int*    chunkC = (int*)   (ws + WS_CHUNK);
    int*    selds  = (int*)   (ws + WS_SELDS);
    int*    seldr  = (int*)   (ws + WS_SELDR);

    hipLaunchKernelGGL(k_transposeW, dim3(CC), dim3(CC), 0, stream, Wq, Wv, WTq, WTv);
    hipLaunchKernelGGL(k_transposeX, dim3(NN/32, CC/32, BB), dim3(256), 0, stream, x, xT);
    hipLaunchKernelGGL(k_sq, dim3((BB*NN + 255)/256), dim3(256), 0, stream, xT, sqF);
    hipLaunchKernelGGL(k_proj, dim3(BB*NN), dim3(CC), 0, stream, xT, WTq, WTv, qT, vxT);
    hipLaunchKernelGGL(k_knn, dim3(BB*NN/GN), dim3(256), 0, stream, xT, sqF, knn);
    hipLaunchKernelGGL(k_energy, dim3(BB*NN), dim3(CC), 0, stream, xT, qT, Wk, knn, attnF, stdF);

    hipMemsetAsync(counts, 0, BB*NN*4, stream);
    hipLaunchKernelGGL(k_count, dim3((BB*NN*KNB + 255)/256), dim3(256), 0, stream, knn, counts);
    hipLaunchKernelGGL(k_scan, dim3(BB), dim3(256), 0, stream, counts, off);
    hipLaunchKernelGGL(k_chunkcount, dim3(BB*NCHUNK), dim3(256), 0, stream, knn, chunkC);
    hipLaunchKernelGGL(k_chunkscan, dim3((BB*NN + 255)/256), dim3(256), 0, stream, chunkC);
    hipLaunchKernelGGL(k_fill2, dim3(BB*NCHUNK), dim3(256), 0, stream, knn, off, chunkC, slots);
    hipLaunchKernelGGL(k_segsum, dim3((BB*NN + 255)/256), dim3(256), 0, stream, off, counts, slots, attnF, score);

    hipLaunchKernelGGL(k_topsort2, dim3(2*BB), dim3(256), 0, stream, score, stdF, out, selds, seldr);

    hipLaunchKernelGGL(k_gather, dim3(BB*(MSEL + NDROP)), dim3(CC), 0, stream, vxT, attnF, knn, selds, seldr, out);
}

// Round 11
// 1428.406 us; speedup vs baseline: 30.4159x; 1.3668x over previous
//
#include <hip/hip_runtime.h>
#include <float.h>
#include <math.h>

#define BB 2
#define CC 128
#define NN 4096
#define KNB 32
#define KSEL 40
#define GN 4
#define MSEL 2048
#define NDROP 2048
#define CHUNKSZ 1024
#define NCHUNK 128   // NN*KNB / CHUNKSZ per batch

// ---------------- workspace layout (bytes) ----------------
#define WS_WTQ    0
#define WS_WTV    (WS_WTQ + CC*CC*4)
#define WS_SQF    (WS_WTV + CC*CC*4)                 // float[BB*NN]
#define WS_XT     (WS_SQF + BB*NN*4)                 // float[BB*NN*CC] (x transposed)
#define WS_QT     (WS_XT  + BB*NN*CC*4)              // float[BB*NN*CC]
#define WS_VXT    (WS_QT  + BB*NN*CC*4)              // float[BB*NN*CC]
#define WS_KNN    (WS_VXT + BB*NN*CC*4)              // int
#define WS_ATTNF  (WS_KNN + BB*NN*KNB*4)             // float
#define WS_STD    (WS_ATTNF + BB*NN*KNB*4)           // float[BB*NN]
#define WS_SCORE  (WS_STD + BB*NN*4)                 // float[BB*NN]
#define WS_COUNTS (WS_SCORE + BB*NN*4)
#define WS_OFF    (WS_COUNTS + BB*NN*4)
#define WS_SLOTS  (WS_OFF + BB*NN*4)
#define WS_CHUNK  (WS_SLOTS + BB*NN*KNB*4)           // int[BB][NCHUNK][NN] = 4MB
#define WS_SELDS  (WS_CHUNK + BB*NCHUNK*NN*4)
#define WS_SELDR  (WS_SELDS + BB*MSEL*4)
#define WS_END    (WS_SELDR + BB*NDROP*4)

// ---------------- output layout (floats) ----------------
#define OUT_XDS  0
#define OUT_IDX  (BB*CC*MSEL)
#define OUT_XDR  (OUT_IDX + BB*MSEL)
#define OUT_IDXD (OUT_XDR + BB*CC*NDROP)

// XLA:CPU-style sequential reduction over 32 contiguous fp32 (unfused adds).
__device__ __forceinline__ float seq32(const float* a) {
    float acc = a[0];
    #pragma unroll
    for (int i = 1; i < 32; ++i) acc = __fadd_rn(acc, a[i]);
    return acc;
}

// XLA lowers exp -> libm expf (nearly correctly rounded): emulate via double.
__device__ __forceinline__ float xla_expf(float x) {
    return (float)exp((double)x);
}

__global__ void k_transposeW(const float* __restrict__ Wq, const float* __restrict__ Wv,
                             float* __restrict__ WTq, float* __restrict__ WTv) {
    int c = blockIdx.x, o = threadIdx.x;
    WTq[c*CC + o] = Wq[o*CC + c];
    WTv[c*CC + o] = Wv[o*CC + c];
}

// x [b][c][n] -> xT [b][n][c] (LDS tile transpose; values untouched)
__global__ __launch_bounds__(256) void k_transposeX(const float* __restrict__ x,
                                                    float* __restrict__ xT) {
    __shared__ float t[32][33];
    int b  = blockIdx.z;
    int n0 = blockIdx.x * 32;
    int c0 = blockIdx.y * 32;
    int tx = threadIdx.x & 31, ty = threadIdx.x >> 5;  // 32 x 8
    const float* xb = x + (size_t)b*CC*NN;
    for (int r = ty; r < 32; r += 8)
        t[r][tx] = xb[(size_t)(c0+r)*NN + n0 + tx];
    __syncthreads();
    float* xo = xT + (size_t)b*NN*CC;
    for (int r = ty; r < 32; r += 8)
        xo[(size_t)(n0+r)*CC + c0 + tx] = t[tx][r];
}

// sqF: fp32 sequential over c (exact ref-emu; reads xT row contiguously).
__global__ void k_sq(const float* __restrict__ xT, float* __restrict__ sqF) {
    int i = blockIdx.x*blockDim.x + threadIdx.x;
    if (i >= BB*NN) return;
    const float* row = xT + (size_t)i*CC;
    float sf = 0.f;
    for (int c = 0; c < CC; ++c)
        sf = __fadd_rn(sf, __fmul_rn(row[c], row[c]));
    sqF[i] = sf;
}

// q: XLA-emu (sequential over c, FMA). v: plain fp32 (lenient outputs).
__global__ __launch_bounds__(CC) void k_proj(const float* __restrict__ xT,
                                             const float* __restrict__ WTq,
                                             const float* __restrict__ WTv,
                                             float* __restrict__ qT,
                                             float* __restrict__ vxT) {
    int bn = blockIdx.x;
    int o = threadIdx.x;
    __shared__ float xs[CC];
    xs[o] = xT[(size_t)bn*CC + o];
    __syncthreads();
    float aq = 0.f, av = 0.f;
    for (int c = 0; c < CC; ++c) {
        float xv = xs[c];
        aq = fmaf(WTq[c*CC + o], xv, aq);
        av = fmaf(WTv[c*CC + o], xv, av);
    }
    size_t base = (size_t)bn*CC + o;
    qT[base] = aq; vxT[base] = av;
}

// KNN v3: fp32 gram with coalesced [c][n] loads + register accumulators;
// two-level cached argmin selection of top-KSEL superset; exact re-rank
// by ref-emulated fp32 dist (FROZEN arithmetic) -> top-32 order.
__global__ __launch_bounds__(256) void k_knn(const float* __restrict__ x,
                                             const float* __restrict__ xT,
                                             const float* __restrict__ sqF,
                                             int* __restrict__ knn) {
    __shared__ float xs[GN][CC];
    __shared__ float dist[GN][NN];
    __shared__ int   candIdx[GN][KSEL];
    __shared__ float candDist[GN][KSEL];
    int blk = blockIdx.x;
    int b  = blk / (NN/GN);
    int n0 = (blk % (NN/GN)) * GN;
    int tid = threadIdx.x;
    const float* xb  = x  + (size_t)b*CC*NN;
    const float* xbT = xT + (size_t)b*NN*CC;
    const float* sqf = sqF + b*NN;
    for (int i = tid; i < GN*CC; i += 256) {
        int g = i / CC, c = i % CC;
        xs[g][c] = xbT[(size_t)(n0+g)*CC + c];
    }
    __syncthreads();
    // ---- gram: thread owns m in [16*tid, 16*tid+16) as 4 float4 chunks ----
    float4 acc[GN][4];
    #pragma unroll
    for (int g = 0; g < GN; ++g)
        #pragma unroll
        for (int u = 0; u < 4; ++u)
            acc[g][u] = make_float4(0.f, 0.f, 0.f, 0.f);
    int m0 = tid * 16;
    for (int c = 0; c < CC; ++c) {
        float q0 = xs[0][c], q1 = xs[1][c], q2 = xs[2][c], q3 = xs[3][c];
        const float4* row = (const float4*)(xb + (size_t)c*NN + m0);
        #pragma unroll
        for (int u = 0; u < 4; ++u) {
            float4 xv = row[u];
            acc[0][u].x += q0*xv.x; acc[0][u].y += q0*xv.y; acc[0][u].z += q0*xv.z; acc[0][u].w += q0*xv.w;
            acc[1][u].x += q1*xv.x; acc[1][u].y += q1*xv.y; acc[1][u].z += q1*xv.z; acc[1][u].w += q1*xv.w;
            acc[2][u].x += q2*xv.x; acc[2][u].y += q2*xv.y; acc[2][u].z += q2*xv.z; acc[2][u].w += q2*xv.w;
            acc[3][u].x += q3*xv.x; acc[3][u].y += q3*xv.y; acc[3][u].z += q3*xv.z; acc[3][u].w += q3*xv.w;
        }
    }
    {
        float sqn0 = sqf[n0+0], sqn1 = sqf[n0+1], sqn2 = sqf[n0+2], sqn3 = sqf[n0+3];
        const float4* sqm4 = (const float4*)(sqf + m0);
        #pragma unroll
        for (int u = 0; u < 4; ++u) {
            float4 sm = sqm4[u];
            float4 d0, d1, d2, d3;
            d0.x = sqn0 + sm.x - 2.f*acc[0][u].x; d0.y = sqn0 + sm.y - 2.f*acc[0][u].y;
            d0.z = sqn0 + sm.z - 2.f*acc[0][u].z; d0.w = sqn0 + sm.w - 2.f*acc[0][u].w;
            d1.x = sqn1 + sm.x - 2.f*acc[1][u].x; d1.y = sqn1 + sm.y - 2.f*acc[1][u].y;
            d1.z = sqn1 + sm.z - 2.f*acc[1][u].z; d1.w = sqn1 + sm.w - 2.f*acc[1][u].w;
            d2.x = sqn2 + sm.x - 2.f*acc[2][u].x; d2.y = sqn2 + sm.y - 2.f*acc[2][u].y;
            d2.z = sqn2 + sm.z - 2.f*acc[2][u].z; d2.w = sqn2 + sm.w - 2.f*acc[2][u].w;
            d3.x = sqn3 + sm.x - 2.f*acc[3][u].x; d3.y = sqn3 + sm.y - 2.f*acc[3][u].y;
            d3.z = sqn3 + sm.z - 2.f*acc[3][u].z; d3.w = sqn3 + sm.w - 2.f*acc[3][u].w;
            *(float4*)&dist[0][m0 + 4*u] = d0;
            *(float4*)&dist[1][m0 + 4*u] = d1;
            *(float4*)&dist[2][m0 + 4*u] = d2;
            *(float4*)&dist[3][m0 + 4*u] = d3;
        }
    }
    __syncthreads();
    // ---- selection: wave w owns query w; lane owns m = lane + 64*i ----
    int wid = tid >> 6, lane = tid & 63;
    {
        float* dr = dist[wid];
        float gmv[8]; int gmi[8];
        #pragma unroll
        for (int gi = 0; gi < 8; ++gi) {
            float bv = FLT_MAX; int bi = NN;
            #pragma unroll
            for (int i2 = 0; i2 < 8; ++i2) {
                int m = lane + 64*(gi*8 + i2);
                float v = dr[m];
                if (v < bv) { bv = v; bi = m; }
            }
            gmv[gi] = bv; gmi[gi] = bi;
        }
        for (int kk = 0; kk < KSEL; ++kk) {
            float lv = gmv[0]; int li = gmi[0];
            #pragma unroll
            for (int gi = 1; gi < 8; ++gi)
                if (gmv[gi] < lv || (gmv[gi] == lv && gmi[gi] < li)) { lv = gmv[gi]; li = gmi[gi]; }
            float bv = lv; int bi = li;
            for (int off = 32; off > 0; off >>= 1) {
                float ov = __shfl_xor(bv, off);
                int   oi = __shfl_xor(bi, off);
                if (ov < bv || (ov == bv && oi < bi)) { bv = ov; bi = oi; }
            }
            if (lane == 0) candIdx[wid][kk] = bi;
            if ((bi & 63) == lane) {
                dr[bi] = FLT_MAX;
                int gsel = (bi >> 6) >> 3;
                #pragma unroll
                for (int GI = 0; GI < 8; ++GI) if (GI == gsel) {
                    float bv2 = FLT_MAX; int bi2 = NN;
                    #pragma unroll
                    for (int i2 = 0; i2 < 8; ++i2) {
                        int m = lane + 64*(GI*8 + i2);
                        float v = dr[m];
                        if (v < bv2 || (v == bv2 && m < bi2)) { bv2 = v; bi2 = m; }
                    }
                    gmv[GI] = bv2; gmi[GI] = bi2;
                }
            }
        }
    }
    __syncthreads();
    // ---- re-rank by ref-emulated fp32 dist (sequential unfused; FROZEN) ----
    int g = tid >> 6, j = tid & 63;
    if (j < KSEL) {
        int m = candIdx[g][j];
        const float* colm = xbT + (size_t)m*CC;
        float acc2 = 0.f;
        for (int c = 0; c < CC; ++c)
            acc2 = __fadd_rn(acc2, __fmul_rn(xs[g][c], colm[c]));
        candDist[g][j] = __fsub_rn(__fadd_rn(sqf[n0+g], sqf[m]), __fmul_rn(2.0f, acc2));
    }
    __syncthreads();
    if (j < KSEL) {
        float dme = candDist[g][j]; int ime = candIdx[g][j];
        int rank = 0;
        for (int t = 0; t < KSEL; ++t) {
            float dt = candDist[g][t]; int it = candIdx[g][t];
            if (dt < dme || (dt == dme && it < ime)) ++rank;
        }
        if (rank < KNB)
            knn[((size_t)b*NN + n0 + g)*KNB + rank] = ime;
    }
}

// XLA-emu of k = Wk @ (x_m - x_n), energy = q . k (sequential FMA), then
// softmax + std with SEQUENTIAL 32-length reductions (XLA reduce order).
__global__ __launch_bounds__(CC) void k_energy(const float* __restrict__ xT,
                                               const float* __restrict__ qT,
                                               const float* __restrict__ Wk,
                                               const int* __restrict__ knn,
                                               float* __restrict__ attnF,
                                               float* __restrict__ stdF) {
    int bn = blockIdx.x;
    int b = bn / NN;
    int o = threadIdx.x;
    __shared__ float xn[CC];
    __shared__ float qs[CC];
    __shared__ int   mIdx[KNB];
    __shared__ float nb[KNB][CC];
    __shared__ float kmat[KNB][CC];
    __shared__ float es[KNB];
    const float* xbT = xT + (size_t)b*NN*CC;
    xn[o] = xT[(size_t)bn*CC + o];
    qs[o] = qT[(size_t)bn*CC + o];
    if (o < KNB) mIdx[o] = knn[(size_t)bn*KNB + o];
    __syncthreads();
    #pragma unroll
    for (int kk = 0; kk < KNB; ++kk)
        nb[kk][o] = __fsub_rn(xbT[(size_t)mIdx[kk]*CC + o], xn[o]);
    __syncthreads();
    float acc[KNB];
    #pragma unroll
    for (int kk = 0; kk < KNB; ++kk) acc[kk] = 0.f;
    const float* wrow = Wk + (size_t)o*CC;
    for (int c = 0; c < CC; ++c) {
        float w = wrow[c];
        #pragma unroll
        for (int kk = 0; kk < KNB; ++kk)
            acc[kk] = fmaf(w, nb[kk][c], acc[kk]);
    }
    #pragma unroll
    for (int kk = 0; kk < KNB; ++kk) kmat[kk][o] = acc[kk];
    __syncthreads();
    if (o < KNB) {
        float e = 0.f;
        for (int d = 0; d < CC; ++d)
            e = fmaf(qs[d], kmat[o][d], e);
        es[o] = __fdiv_rn(e, __fsqrt_rn(128.0f));
    }
    __syncthreads();
    if (o == 0) {
        float mx = es[0];
        #pragma unroll
        for (int kk = 1; kk < KNB; ++kk) mx = fmaxf(mx, es[kk]);
        float p[KNB], a[KNB], d2[KNB];
        #pragma unroll
        for (int kk = 0; kk < KNB; ++kk)
            p[kk] = xla_expf(__fsub_rn(es[kk], mx));
        float s = seq32(p);
        #pragma unroll
        for (int kk = 0; kk < KNB; ++kk) {
            a[kk] = __fdiv_rn(p[kk], s);
            attnF[(size_t)bn*KNB + kk] = a[kk];
        }
        float mean = __fdiv_rn(seq32(a), 32.0f);
        #pragma unroll
        for (int kk = 0; kk < KNB; ++kk) {
            float dd = __fsub_rn(a[kk], mean);
            d2[kk] = __fmul_rn(dd, dd);
        }
        float var = __fdiv_rn(seq32(d2), 32.0f);
        stdF[bn] = __fsqrt_rn(var);
    }
}

__global__ void k_count(const int* __restrict__ knn, int* __restrict__ counts) {
    int i = blockIdx.x*blockDim.x + threadIdx.x;
    if (i >= BB*NN*KNB) return;
    int b = i / (NN*KNB);
    atomicAdd(&counts[b*NN + knn[i]], 1);
}

__global__ __launch_bounds__(256) void k_scan(const int* __restrict__ counts, int* __restrict__ off) {
    int b = blockIdx.x;
    const int* c = counts + b*NN;
    int* o = off + b*NN;
    __shared__ int part[256];
    __shared__ int partScan[256];
    int tid = threadIdx.x;
    int base = tid*16;
    int s = 0;
    for (int i = 0; i < 16; ++i) s += c[base+i];
    part[tid] = s;
    __syncthreads();
    if (tid == 0) { int a = 0; for (int i = 0; i < 256; ++i) { partScan[i] = a; a += part[i]; } }
    __syncthreads();
    int a = partScan[tid];
    for (int i = 0; i < 16; ++i) { o[base+i] = a; a += c[base+i]; }
}

// Per-chunk histogram over segment ids (deterministic; LDS atomics).
__global__ __launch_bounds__(256) void k_chunkcount(const int* __restrict__ knn,
                                                    int* __restrict__ chunkCnt) {
    __shared__ int hist[NN];
    int b = blockIdx.x / NCHUNK, p = blockIdx.x % NCHUNK;
    int tid = threadIdx.x;
    for (int i = tid; i < NN; i += 256) hist[i] = 0;
    __syncthreads();
    const int* kb = knn + (size_t)b*NN*KNB + (size_t)p*CHUNKSZ;
    for (int i = tid; i < CHUNKSZ; i += 256)
        atomicAdd(&hist[kb[i]], 1);
    __syncthreads();
    int* row = chunkCnt + ((size_t)b*NCHUNK + p)*NN;
    for (int i = tid; i < NN; i += 256) row[i] = hist[i];
}

// Per (b,m): exclusive scan of chunkCnt over chunks (in place).
__global__ __launch_bounds__(256) void k_chunkscan(int* __restrict__ chunkCnt) {
    int i = blockIdx.x*blockDim.x + threadIdx.x;
    if (i >= BB*NN) return;
    int b = i / NN, m = i % NN;
    int running = 0;
    for (int p = 0; p < NCHUNK; ++p) {
        size_t idx = ((size_t)b*NCHUNK + p)*NN + m;
        int t = chunkCnt[idx];
        chunkCnt[idx] = running;
        running += t;
    }
}

// Stable fill: local rank within chunk (#earlier same-m elements) + chunk base.
__global__ __launch_bounds__(256) void k_fill2(const int* __restrict__ knn,
                                               const int* __restrict__ off,
                                               const int* __restrict__ chunkCnt,
                                               int* __restrict__ slots) {
    __shared__ int mv[CHUNKSZ];
    int b = blockIdx.x / NCHUNK, p = blockIdx.x % NCHUNK;
    int tid = threadIdx.x;
    const int* kb = knn + (size_t)b*NN*KNB + (size_t)p*CHUNKSZ;
    for (int i = tid; i < CHUNKSZ; i += 256) mv[i] = kb[i];
    __syncthreads();
    const int* cbase = chunkCnt + ((size_t)b*NCHUNK + p)*NN;
    const int* ob    = off + b*NN;
    int* sb = slots + (size_t)b*NN*KNB;
    for (int i = tid; i < CHUNKSZ; i += 256) {
        int m = mv[i];
        int rank = 0;
        for (int j = 0; j < i; ++j) rank += (mv[j] == m);
        sb[ob[m] + cbase[m] + rank] = p*CHUNKSZ + i;
    }
}

// Segment sum in ascending (n,k) order, sequential fp32 unfused adds.
__global__ void k_segsum(const int* __restrict__ off, const int* __restrict__ counts,
                         const int* __restrict__ slots, const float* __restrict__ attn,
                         float* __restrict__ score) {
    int i = blockIdx.x*blockDim.x + threadIdx.x;
    if (i >= BB*NN) return;
    int b = i / NN;
    int o = off[i], cnt = counts[i];
    const int* s = slots + (size_t)b*NN*KNB + o;
    const float* ab = attn + (size_t)b*NN*KNB;
    float acc = 0.f;
    for (int a = 0; a < cnt; ++a) acc = __fadd_rn(acc, ab[s[a]]);
    score[i] = acc;
}

// Merged bitonic sorts: blocks [0,BB) sort score DESC; [BB,2BB) sort std ASC.
__global__ __launch_bounds__(256) void k_topsort2(const float* __restrict__ score,
                                                  const float* __restrict__ stdv,
                                                  float* __restrict__ out,
                                                  int* __restrict__ selds,
                                                  int* __restrict__ seldr) {
    int blk = blockIdx.x;
    bool desc = blk < BB;
    int b = desc ? blk : blk - BB;
    const float* val = (desc ? score : stdv) + b*NN;
    __shared__ float v[NN];
    __shared__ int  id[NN];
    for (int i = threadIdx.x; i < NN; i += 256) { v[i] = val[i]; id[i] = i; }
    __syncthreads();
    for (int k = 2; k <= NN; k <<= 1) {
        for (int j = k >> 1; j > 0; j >>= 1) {
            for (int i = threadIdx.x; i < NN; i += 256) {
                int ixj = i ^ j;
                if (ixj > i) {
                    float va = v[i], vb = v[ixj];
                    int ia = id[i], ib = id[ixj];
                    bool before = desc ? (va > vb || (va == vb && ia < ib))
                                       : (va < vb || (va == vb && ia < ib));
                    bool up = ((i & k) == 0);
                    if (up ? !before : before) {
                        v[i] = vb; v[ixj] = va; id[i] = ib; id[ixj] = ia;
                    }
                }
            }
            __syncthreads();
        }
    }
    float* idx_out = out + (desc ? OUT_IDX : OUT_IDXD) + b*MSEL;
    int*   sel_out = (desc ? selds : seldr) + b*MSEL;
    for (int i = threadIdx.x; i < MSEL; i += 256) {
        idx_out[i] = (float)id[i];
        sel_out[i] = id[i];
    }
}

// out[b,c,j] = sum_k attn[nsel,k]*(vxT[m_k,c]-vxT[nsel,c])
__global__ __launch_bounds__(CC) void k_gather(const float* __restrict__ vxT,
                                               const float* __restrict__ attn,
                                               const int* __restrict__ knn,
                                               const int* __restrict__ sel_ds,
                                               const int* __restrict__ sel_dr,
                                               float* __restrict__ out) {
    int blk = blockIdx.x;
    int c = threadIdx.x;
    bool dropped = false;
    if (blk >= BB*MSEL) { dropped = true; blk -= BB*MSEL; }
    int b = blk / MSEL, jj = blk % MSEL;
    int nsel = dropped ? sel_dr[b*NDROP + jj] : sel_ds[b*MSEL + jj];
    const float* arow = attn + ((size_t)b*NN + nsel)*KNB;
    const int*   krow = knn  + ((size_t)b*NN + nsel)*KNB;
    const float* vb   = vxT  + (size_t)b*NN*CC;
    __shared__ float a_s[KNB];
    __shared__ int   m_s[KNB];
    __shared__ float vn[CC];
    if (c < KNB) { a_s[c] = arow[c]; m_s[c] = krow[c]; }
    vn[c] = vb[(size_t)nsel*CC + c];
    __syncthreads();
    float acc = 0.f;
    for (int k = 0; k < KNB; ++k)
        acc += a_s[k] * (vb[(size_t)m_s[k]*CC + c] - vn[c]);
    float* obase = out + (dropped ? OUT_XDR : OUT_XDS);
    obase[((size_t)b*CC + c)*MSEL + jj] = acc;
}

extern "C" void kernel_launch(void* const* d_in, const int* in_sizes, int n_in,
                              void* d_out, int out_size, void* d_ws, size_t ws_size,
                              hipStream_t stream) {
    const float* x  = (const float*)d_in[0];
    const float* Wq = (const float*)d_in[1];
    const float* Wk = (const float*)d_in[2];
    const float* Wv = (const float*)d_in[3];
    float* out = (float*)d_out;
    char* ws = (char*)d_ws;

    float*  WTq    = (float*) (ws + WS_WTQ);
    float*  WTv    = (float*) (ws + WS_WTV);
    float*  sqF    = (float*) (ws + WS_SQF);
    float*  xT     = (float*) (ws + WS_XT);
    float*  qT     = (float*) (ws + WS_QT);
    float*  vxT    = (float*) (ws + WS_VXT);
    int*    knn    = (int*)   (ws + WS_KNN);
    float*  attnF  = (float*) (ws + WS_ATTNF);
    float*  stdF   = (float*) (ws + WS_STD);
    float*  score  = (float*) (ws + WS_SCORE);
    int*    counts = (int*)   (ws + WS_COUNTS);
    int*    off    = (int*)   (ws + WS_OFF);
    int*    slots  = (int*)   (ws + WS_SLOTS);
    int*    chunkC = (int*)   (ws + WS_CHUNK);
    int*    selds  = (int*)   (ws + WS_SELDS);
    int*    seldr  = (int*)   (ws + WS_SELDR);

    hipLaunchKernelGGL(k_transposeW, dim3(CC), dim3(CC), 0, stream, Wq, Wv, WTq, WTv);
    hipLaunchKernelGGL(k_transposeX, dim3(NN/32, CC/32, BB), dim3(256), 0, stream, x, xT);
    hipLaunchKernelGGL(k_sq, dim3((BB*NN + 255)/256), dim3(256), 0, stream, xT, sqF);
    hipLaunchKernelGGL(k_proj, dim3(BB*NN), dim3(CC), 0, stream, xT, WTq, WTv, qT, vxT);
    hipLaunchKernelGGL(k_knn, dim3(BB*NN/GN), dim3(256), 0, stream, x, xT, sqF, knn);
    hipLaunchKernelGGL(k_energy, dim3(BB*NN), dim3(CC), 0, stream, xT, qT, Wk, knn, attnF, stdF);

    hipMemsetAsync(counts, 0, BB*NN*4, stream);
    hipLaunchKernelGGL(k_count, dim3((BB*NN*KNB + 255)/256), dim3(256), 0, stream, knn, counts);
    hipLaunchKernelGGL(k_scan, dim3(BB), dim3(256), 0, stream, counts, off);
    hipLaunchKernelGGL(k_chunkcount, dim3(BB*NCHUNK), dim3(256), 0, stream, knn, chunkC);
    hipLaunchKernelGGL(k_chunkscan, dim3((BB*NN + 255)/256), dim3(256), 0, stream, chunkC);
    hipLaunchKernelGGL(k_fill2, dim3(BB*NCHUNK), dim3(256), 0, stream, knn, off, chunkC, slots);
    hipLaunchKernelGGL(k_segsum, dim3((BB*NN + 255)/256), dim3(256), 0, stream, off, counts, slots, attnF, score);

    hipLaunchKernelGGL(k_topsort2, dim3(2*BB), dim3(256), 0, stream, score, stdF, out, selds, seldr);

    hipLaunchKernelGGL(k_gather, dim3(BB*(MSEL + NDROP)), dim3(CC), 0, stream, vxT, attnF, knn, selds, seldr, out);
}

// Round 13
// 1419.680 us; speedup vs baseline: 30.6029x; 1.0061x over previous
//
#include <hip/hip_runtime.h>
#include <float.h>
#include <math.h>

#define BB 2
#define CC 128
#define NN 4096
#define KNB 32
#define KSEL 40
#define GN 4
#define MSEL 2048
#define NDROP 2048
#define CHUNKSZ 1024
#define NCHUNK 128   // NN*KNB / CHUNKSZ per batch
#define TJ 16        // gather j-tile

// ---------------- workspace layout (bytes) ----------------
#define WS_WTQ    0
#define WS_WTV    (WS_WTQ + CC*CC*4)
#define WS_SQF    (WS_WTV + CC*CC*4)                 // float[BB*NN]
#define WS_XT     (WS_SQF + BB*NN*4)                 // float[BB*NN*CC] (x transposed)
#define WS_QT     (WS_XT  + BB*NN*CC*4)              // float[BB*NN*CC]
#define WS_VXT    (WS_QT  + BB*NN*CC*4)              // float[BB*NN*CC]
#define WS_KNN    (WS_VXT + BB*NN*CC*4)              // int
#define WS_ATTNF  (WS_KNN + BB*NN*KNB*4)             // float
#define WS_STD    (WS_ATTNF + BB*NN*KNB*4)           // float[BB*NN]
#define WS_SCORE  (WS_STD + BB*NN*4)                 // float[BB*NN]
#define WS_COUNTS (WS_SCORE + BB*NN*4)
#define WS_OFF    (WS_COUNTS + BB*NN*4)
#define WS_SLOTS  (WS_OFF + BB*NN*4)
#define WS_CHUNK  (WS_SLOTS + BB*NN*KNB*4)           // int[BB][NCHUNK][NN] = 4MB
#define WS_SELDS  (WS_CHUNK + BB*NCHUNK*NN*4)
#define WS_SELDR  (WS_SELDS + BB*MSEL*4)
#define WS_END    (WS_SELDR + BB*NDROP*4)

// ---------------- output layout (floats) ----------------
#define OUT_XDS  0
#define OUT_IDX  (BB*CC*MSEL)
#define OUT_XDR  (OUT_IDX + BB*MSEL)
#define OUT_IDXD (OUT_XDR + BB*CC*NDROP)

// XLA:CPU-style sequential reduction over 32 contiguous fp32 (unfused adds).
__device__ __forceinline__ float seq32(const float* a) {
    float acc = a[0];
    #pragma unroll
    for (int i = 1; i < 32; ++i) acc = __fadd_rn(acc, a[i]);
    return acc;
}

// XLA lowers exp -> libm expf (nearly correctly rounded): emulate via double.
__device__ __forceinline__ float xla_expf(float x) {
    return (float)exp((double)x);
}

__global__ void k_transposeW(const float* __restrict__ Wq, const float* __restrict__ Wv,
                             float* __restrict__ WTq, float* __restrict__ WTv) {
    int c = blockIdx.x, o = threadIdx.x;
    WTq[c*CC + o] = Wq[o*CC + c];
    WTv[c*CC + o] = Wv[o*CC + c];
}

// x [b][c][n] -> xT [b][n][c] (LDS tile transpose; values untouched)
__global__ __launch_bounds__(256) void k_transposeX(const float* __restrict__ x,
                                                    float* __restrict__ xT) {
    __shared__ float t[32][33];
    int b  = blockIdx.z;
    int n0 = blockIdx.x * 32;
    int c0 = blockIdx.y * 32;
    int tx = threadIdx.x & 31, ty = threadIdx.x >> 5;  // 32 x 8
    const float* xb = x + (size_t)b*CC*NN;
    for (int r = ty; r < 32; r += 8)
        t[r][tx] = xb[(size_t)(c0+r)*NN + n0 + tx];
    __syncthreads();
    float* xo = xT + (size_t)b*NN*CC;
    for (int r = ty; r < 32; r += 8)
        xo[(size_t)(n0+r)*CC + c0 + tx] = t[tx][r];
}

// sqF: fp32 sequential over c (exact ref-emu; reads xT row contiguously).
__global__ void k_sq(const float* __restrict__ xT, float* __restrict__ sqF) {
    int i = blockIdx.x*blockDim.x + threadIdx.x;
    if (i >= BB*NN) return;
    const float* row = xT + (size_t)i*CC;
    float sf = 0.f;
    for (int c = 0; c < CC; ++c)
        sf = __fadd_rn(sf, __fmul_rn(row[c], row[c]));
    sqF[i] = sf;
}

// q: XLA-emu (sequential over c, FMA). v: plain fp32 (lenient outputs).
// (round-11 verbatim — FROZEN)
__global__ __launch_bounds__(CC) void k_proj(const float* __restrict__ xT,
                                             const float* __restrict__ WTq,
                                             const float* __restrict__ WTv,
                                             float* __restrict__ qT,
                                             float* __restrict__ vxT) {
    int bn = blockIdx.x;
    int o = threadIdx.x;
    __shared__ float xs[CC];
    xs[o] = xT[(size_t)bn*CC + o];
    __syncthreads();
    float aq = 0.f, av = 0.f;
    for (int c = 0; c < CC; ++c) {
        float xv = xs[c];
        aq = fmaf(WTq[c*CC + o], xv, aq);
        av = fmaf(WTv[c*CC + o], xv, av);
    }
    size_t base = (size_t)bn*CC + o;
    qT[base] = aq; vxT[base] = av;
}

// KNN v4: fp32 gram with coalesced [c][n] loads + register accumulators
// (c-loop unrolled x4 for VMEM ILP — verified innocent in round 12);
// two-level cached argmin selection; exact re-rank by ref-emulated fp32 dist.
__global__ __launch_bounds__(256) void k_knn(const float* __restrict__ x,
                                             const float* __restrict__ xT,
                                             const float* __restrict__ sqF,
                                             int* __restrict__ knn) {
    __shared__ float xs[GN][CC];
    __shared__ float dist[GN][NN];
    __shared__ int   candIdx[GN][KSEL];
    __shared__ float candDist[GN][KSEL];
    int blk = blockIdx.x;
    int b  = blk / (NN/GN);
    int n0 = (blk % (NN/GN)) * GN;
    int tid = threadIdx.x;
    const float* xb  = x  + (size_t)b*CC*NN;
    const float* xbT = xT + (size_t)b*NN*CC;
    const float* sqf = sqF + b*NN;
    for (int i = tid; i < GN*CC; i += 256) {
        int g = i / CC, c = i % CC;
        xs[g][c] = xbT[(size_t)(n0+g)*CC + c];
    }
    __syncthreads();
    // ---- gram: thread owns m in [16*tid, 16*tid+16) as 4 float4 chunks ----
    float4 acc[GN][4];
    #pragma unroll
    for (int g = 0; g < GN; ++g)
        #pragma unroll
        for (int u = 0; u < 4; ++u)
            acc[g][u] = make_float4(0.f, 0.f, 0.f, 0.f);
    int m0 = tid * 16;
    #pragma unroll 4
    for (int c = 0; c < CC; ++c) {
        float q0 = xs[0][c], q1 = xs[1][c], q2 = xs[2][c], q3 = xs[3][c];
        const float4* row = (const float4*)(xb + (size_t)c*NN + m0);
        #pragma unroll
        for (int u = 0; u < 4; ++u) {
            float4 xv = row[u];
            acc[0][u].x += q0*xv.x; acc[0][u].y += q0*xv.y; acc[0][u].z += q0*xv.z; acc[0][u].w += q0*xv.w;
            acc[1][u].x += q1*xv.x; acc[1][u].y += q1*xv.y; acc[1][u].z += q1*xv.z; acc[1][u].w += q1*xv.w;
            acc[2][u].x += q2*xv.x; acc[2][u].y += q2*xv.y; acc[2][u].z += q2*xv.z; acc[2][u].w += q2*xv.w;
            acc[3][u].x += q3*xv.x; acc[3][u].y += q3*xv.y; acc[3][u].z += q3*xv.z; acc[3][u].w += q3*xv.w;
        }
    }
    {
        float sqn0 = sqf[n0+0], sqn1 = sqf[n0+1], sqn2 = sqf[n0+2], sqn3 = sqf[n0+3];
        const float4* sqm4 = (const float4*)(sqf + m0);
        #pragma unroll
        for (int u = 0; u < 4; ++u) {
            float4 sm = sqm4[u];
            float4 d0, d1, d2, d3;
            d0.x = sqn0 + sm.x - 2.f*acc[0][u].x; d0.y = sqn0 + sm.y - 2.f*acc[0][u].y;
            d0.z = sqn0 + sm.z - 2.f*acc[0][u].z; d0.w = sqn0 + sm.w - 2.f*acc[0][u].w;
            d1.x = sqn1 + sm.x - 2.f*acc[1][u].x; d1.y = sqn1 + sm.y - 2.f*acc[1][u].y;
            d1.z = sqn1 + sm.z - 2.f*acc[1][u].z; d1.w = sqn1 + sm.w - 2.f*acc[1][u].w;
            d2.x = sqn2 + sm.x - 2.f*acc[2][u].x; d2.y = sqn2 + sm.y - 2.f*acc[2][u].y;
            d2.z = sqn2 + sm.z - 2.f*acc[2][u].z; d2.w = sqn2 + sm.w - 2.f*acc[2][u].w;
            d3.x = sqn3 + sm.x - 2.f*acc[3][u].x; d3.y = sqn3 + sm.y - 2.f*acc[3][u].y;
            d3.z = sqn3 + sm.z - 2.f*acc[3][u].z; d3.w = sqn3 + sm.w - 2.f*acc[3][u].w;
            *(float4*)&dist[0][m0 + 4*u] = d0;
            *(float4*)&dist[1][m0 + 4*u] = d1;
            *(float4*)&dist[2][m0 + 4*u] = d2;
            *(float4*)&dist[3][m0 + 4*u] = d3;
        }
    }
    __syncthreads();
    // ---- selection: wave w owns query w; lane owns m = lane + 64*i ----
    int wid = tid >> 6, lane = tid & 63;
    {
        float* dr = dist[wid];
        float gmv[8]; int gmi[8];
        #pragma unroll
        for (int gi = 0; gi < 8; ++gi) {
            float bv = FLT_MAX; int bi = NN;
            #pragma unroll
            for (int i2 = 0; i2 < 8; ++i2) {
                int m = lane + 64*(gi*8 + i2);
                float v = dr[m];
                if (v < bv) { bv = v; bi = m; }
            }
            gmv[gi] = bv; gmi[gi] = bi;
        }
        for (int kk = 0; kk < KSEL; ++kk) {
            float lv = gmv[0]; int li = gmi[0];
            #pragma unroll
            for (int gi = 1; gi < 8; ++gi)
                if (gmv[gi] < lv || (gmv[gi] == lv && gmi[gi] < li)) { lv = gmv[gi]; li = gmi[gi]; }
            float bv = lv; int bi = li;
            for (int off = 32; off > 0; off >>= 1) {
                float ov = __shfl_xor(bv, off);
                int   oi = __shfl_xor(bi, off);
                if (ov < bv || (ov == bv && oi < bi)) { bv = ov; bi = oi; }
            }
            if (lane == 0) candIdx[wid][kk] = bi;
            if ((bi & 63) == lane) {
                dr[bi] = FLT_MAX;
                int gsel = (bi >> 6) >> 3;
                #pragma unroll
                for (int GI = 0; GI < 8; ++GI) if (GI == gsel) {
                    float bv2 = FLT_MAX; int bi2 = NN;
                    #pragma unroll
                    for (int i2 = 0; i2 < 8; ++i2) {
                        int m = lane + 64*(GI*8 + i2);
                        float v = dr[m];
                        if (v < bv2 || (v == bv2 && m < bi2)) { bv2 = v; bi2 = m; }
                    }
                    gmv[GI] = bv2; gmi[GI] = bi2;
                }
            }
        }
    }
    __syncthreads();
    // ---- re-rank by ref-emulated fp32 dist (sequential unfused; FROZEN) ----
    int g = tid >> 6, j = tid & 63;
    if (j < KSEL) {
        int m = candIdx[g][j];
        const float* colm = xbT + (size_t)m*CC;
        float acc2 = 0.f;
        for (int c = 0; c < CC; ++c)
            acc2 = __fadd_rn(acc2, __fmul_rn(xs[g][c], colm[c]));
        candDist[g][j] = __fsub_rn(__fadd_rn(sqf[n0+g], sqf[m]), __fmul_rn(2.0f, acc2));
    }
    __syncthreads();
    if (j < KSEL) {
        float dme = candDist[g][j]; int ime = candIdx[g][j];
        int rank = 0;
        for (int t = 0; t < KSEL; ++t) {
            float dt = candDist[g][t]; int it = candIdx[g][t];
            if (dt < dme || (dt == dme && it < ime)) ++rank;
        }
        if (rank < KNB)
            knn[((size_t)b*NN + n0 + g)*KNB + rank] = ime;
    }
}

// XLA-emu of k = Wk @ (x_m - x_n), energy = q . k (sequential FMA), then
// softmax + std with SEQUENTIAL 32-length reductions (XLA reduce order).
// (round-11 verbatim — FROZEN; round-12 restructure flipped a std pair)
__global__ __launch_bounds__(CC) void k_energy(const float* __restrict__ xT,
                                               const float* __restrict__ qT,
                                               const float* __restrict__ Wk,
                                               const int* __restrict__ knn,
                                               float* __restrict__ attnF,
                                               float* __restrict__ stdF) {
    int bn = blockIdx.x;
    int b = bn / NN;
    int o = threadIdx.x;
    __shared__ float xn[CC];
    __shared__ float qs[CC];
    __shared__ int   mIdx[KNB];
    __shared__ float nb[KNB][CC];
    __shared__ float kmat[KNB][CC];
    __shared__ float es[KNB];
    const float* xbT = xT + (size_t)b*NN*CC;
    xn[o] = xT[(size_t)bn*CC + o];
    qs[o] = qT[(size_t)bn*CC + o];
    if (o < KNB) mIdx[o] = knn[(size_t)bn*KNB + o];
    __syncthreads();
    #pragma unroll
    for (int kk = 0; kk < KNB; ++kk)
        nb[kk][o] = __fsub_rn(xbT[(size_t)mIdx[kk]*CC + o], xn[o]);
    __syncthreads();
    float acc[KNB];
    #pragma unroll
    for (int kk = 0; kk < KNB; ++kk) acc[kk] = 0.f;
    const float* wrow = Wk + (size_t)o*CC;
    for (int c = 0; c < CC; ++c) {
        float w = wrow[c];
        #pragma unroll
        for (int kk = 0; kk < KNB; ++kk)
            acc[kk] = fmaf(w, nb[kk][c], acc[kk]);
    }
    #pragma unroll
    for (int kk = 0; kk < KNB; ++kk) kmat[kk][o] = acc[kk];
    __syncthreads();
    if (o < KNB) {
        float e = 0.f;
        for (int d = 0; d < CC; ++d)
            e = fmaf(qs[d], kmat[o][d], e);
        es[o] = __fdiv_rn(e, __fsqrt_rn(128.0f));
    }
    __syncthreads();
    if (o == 0) {
        float mx = es[0];
        #pragma unroll
        for (int kk = 1; kk < KNB; ++kk) mx = fmaxf(mx, es[kk]);
        float p[KNB], a[KNB], d2[KNB];
        #pragma unroll
        for (int kk = 0; kk < KNB; ++kk)
            p[kk] = xla_expf(__fsub_rn(es[kk], mx));
        float s = seq32(p);
        #pragma unroll
        for (int kk = 0; kk < KNB; ++kk) {
            a[kk] = __fdiv_rn(p[kk], s);
            attnF[(size_t)bn*KNB + kk] = a[kk];
        }
        float mean = __fdiv_rn(seq32(a), 32.0f);
        #pragma unroll
        for (int kk = 0; kk < KNB; ++kk) {
            float dd = __fsub_rn(a[kk], mean);
            d2[kk] = __fmul_rn(dd, dd);
        }
        float var = __fdiv_rn(seq32(d2), 32.0f);
        stdF[bn] = __fsqrt_rn(var);
    }
}

__global__ void k_count(const int* __restrict__ knn, int* __restrict__ counts) {
    int i = blockIdx.x*blockDim.x + threadIdx.x;
    if (i >= BB*NN*KNB) return;
    int b = i / (NN*KNB);
    atomicAdd(&counts[b*NN + knn[i]], 1);
}

__global__ __launch_bounds__(256) void k_scan(const int* __restrict__ counts, int* __restrict__ off) {
    int b = blockIdx.x;
    const int* c = counts + b*NN;
    int* o = off + b*NN;
    __shared__ int part[256];
    __shared__ int partScan[256];
    int tid = threadIdx.x;
    int base = tid*16;
    int s = 0;
    for (int i = 0; i < 16; ++i) s += c[base+i];
    part[tid] = s;
    __syncthreads();
    if (tid == 0) { int a = 0; for (int i = 0; i < 256; ++i) { partScan[i] = a; a += part[i]; } }
    __syncthreads();
    int a = partScan[tid];
    for (int i = 0; i < 16; ++i) { o[base+i] = a; a += c[base+i]; }
}

// Per-chunk histogram over segment ids (deterministic; LDS atomics).
__global__ __launch_bounds__(256) void k_chunkcount(const int* __restrict__ knn,
                                                    int* __restrict__ chunkCnt) {
    __shared__ int hist[NN];
    int b = blockIdx.x / NCHUNK, p = blockIdx.x % NCHUNK;
    int tid = threadIdx.x;
    for (int i = tid; i < NN; i += 256) hist[i] = 0;
    __syncthreads();
    const int* kb = knn + (size_t)b*NN*KNB + (size_t)p*CHUNKSZ;
    for (int i = tid; i < CHUNKSZ; i += 256)
        atomicAdd(&hist[kb[i]], 1);
    __syncthreads();
    int* row = chunkCnt + ((size_t)b*NCHUNK + p)*NN;
    for (int i = tid; i < NN; i += 256) row[i] = hist[i];
}

// Per (b,m): exclusive scan of chunkCnt over chunks (in place).
__global__ __launch_bounds__(256) void k_chunkscan(int* __restrict__ chunkCnt) {
    int i = blockIdx.x*blockDim.x + threadIdx.x;
    if (i >= BB*NN) return;
    int b = i / NN, m = i % NN;
    int running = 0;
    for (int p = 0; p < NCHUNK; ++p) {
        size_t idx = ((size_t)b*NCHUNK + p)*NN + m;
        int t = chunkCnt[idx];
        chunkCnt[idx] = running;
        running += t;
    }
}

// Stable fill: local rank within chunk (#earlier same-m elements) + chunk base.
__global__ __launch_bounds__(256) void k_fill2(const int* __restrict__ knn,
                                               const int* __restrict__ off,
                                               const int* __restrict__ chunkCnt,
                                               int* __restrict__ slots) {
    __shared__ int mv[CHUNKSZ];
    int b = blockIdx.x / NCHUNK, p = blockIdx.x % NCHUNK;
    int tid = threadIdx.x;
    const int* kb = knn + (size_t)b*NN*KNB + (size_t)p*CHUNKSZ;
    for (int i = tid; i < CHUNKSZ; i += 256) mv[i] = kb[i];
    __syncthreads();
    const int* cbase = chunkCnt + ((size_t)b*NCHUNK + p)*NN;
    const int* ob    = off + b*NN;
    int* sb = slots + (size_t)b*NN*KNB;
    for (int i = tid; i < CHUNKSZ; i += 256) {
        int m = mv[i];
        int rank = 0;
        for (int j = 0; j < i; ++j) rank += (mv[j] == m);
        sb[ob[m] + cbase[m] + rank] = p*CHUNKSZ + i;
    }
}

// Segment sum in ascending (n,k) order, sequential fp32 unfused adds.
__global__ void k_segsum(const int* __restrict__ off, const int* __restrict__ counts,
                         const int* __restrict__ slots, const float* __restrict__ attn,
                         float* __restrict__ score) {
    int i = blockIdx.x*blockDim.x + threadIdx.x;
    if (i >= BB*NN) return;
    int b = i / NN;
    int o = off[i], cnt = counts[i];
    const int* s = slots + (size_t)b*NN*KNB + o;
    const float* ab = attn + (size_t)b*NN*KNB;
    float acc = 0.f;
    for (int a = 0; a < cnt; ++a) acc = __fadd_rn(acc, ab[s[a]]);
    score[i] = acc;
}

// Merged bitonic sorts: blocks [0,BB) sort score DESC; [BB,2BB) sort std ASC.
__global__ __launch_bounds__(256) void k_topsort2(const float* __restrict__ score,
                                                  const float* __restrict__ stdv,
                                                  float* __restrict__ out,
                                                  int* __restrict__ selds,
                                                  int* __restrict__ seldr) {
    int blk = blockIdx.x;
    bool desc = blk < BB;
    int b = desc ? blk : blk - BB;
    const float* val = (desc ? score : stdv) + b*NN;
    __shared__ float v[NN];
    __shared__ int  id[NN];
    for (int i = threadIdx.x; i < NN; i += 256) { v[i] = val[i]; id[i] = i; }
    __syncthreads();
    for (int k = 2; k <= NN; k <<= 1) {
        for (int j = k >> 1; j > 0; j >>= 1) {
            for (int i = threadIdx.x; i < NN; i += 256) {
                int ixj = i ^ j;
                if (ixj > i) {
                    float va = v[i], vb = v[ixj];
                    int ia = id[i], ib = id[ixj];
                    bool before = desc ? (va > vb || (va == vb && ia < ib))
                                       : (va < vb || (va == vb && ia < ib));
                    bool up = ((i & k) == 0);
                    if (up ? !before : before) {
                        v[i] = vb; v[ixj] = va; id[i] = ib; id[ixj] = ia;
                    }
                }
            }
            __syncthreads();
        }
    }
    float* idx_out = out + (desc ? OUT_IDX : OUT_IDXD) + b*MSEL;
    int*   sel_out = (desc ? selds : seldr) + b*MSEL;
    for (int i = threadIdx.x; i < MSEL; i += 256) {
        idx_out[i] = (float)id[i];
        sel_out[i] = id[i];
    }
}

// Tiled gather (verified in round 12): block handles TJ selected columns;
// LDS tile then coalesced writes.
__global__ __launch_bounds__(CC) void k_gather(const float* __restrict__ vxT,
                                               const float* __restrict__ attn,
                                               const int* __restrict__ knn,
                                               const int* __restrict__ sel_ds,
                                               const int* __restrict__ sel_dr,
                                               float* __restrict__ out) {
    __shared__ float a_s[TJ][KNB];
    __shared__ int   m_s[TJ][KNB];
    __shared__ int   nsel_s[TJ];
    __shared__ float tile[TJ][CC];
    int blk = blockIdx.x;
    int c = threadIdx.x;
    const int blocksPerSel = BB*MSEL/TJ;
    bool dropped = false;
    if (blk >= blocksPerSel) { dropped = true; blk -= blocksPerSel; }
    int b  = blk / (MSEL/TJ);
    int j0 = (blk % (MSEL/TJ)) * TJ;
    const int* sel = (dropped ? sel_dr : sel_ds) + b*MSEL;
    if (c < TJ) nsel_s[c] = sel[j0 + c];
    __syncthreads();
    for (int i = c; i < TJ*KNB; i += CC) {
        int j = i / KNB, k = i % KNB;
        int ns = nsel_s[j];
        a_s[j][k] = attn[((size_t)b*NN + ns)*KNB + k];
        m_s[j][k] = knn [((size_t)b*NN + ns)*KNB + k];
    }
    __syncthreads();
    const float* vb = vxT + (size_t)b*NN*CC;
    for (int j = 0; j < TJ; ++j) {
        float vn = vb[(size_t)nsel_s[j]*CC + c];
        float acc = 0.f;
        #pragma unroll
        for (int k = 0; k < KNB; ++k)
            acc += a_s[j][k] * (vb[(size_t)m_s[j][k]*CC + c] - vn);
        tile[j][c] = acc;
    }
    __syncthreads();
    float* obase = out + (dropped ? OUT_XDR : OUT_XDS);
    for (int w = c; w < TJ*CC; w += CC) {
        int j = w & (TJ-1);
        int cc = w >> 4;   // log2(TJ)=4
        obase[((size_t)b*CC + cc)*MSEL + j0 + j] = tile[j][cc];
    }
}

extern "C" void kernel_launch(void* const* d_in, const int* in_sizes, int n_in,
                              void* d_out, int out_size, void* d_ws, size_t ws_size,
                              hipStream_t stream) {
    const float* x  = (const float*)d_in[0];
    const float* Wq = (const float*)d_in[1];
    const float* Wk = (const float*)d_in[2];
    const float* Wv = (const float*)d_in[3];
    float* out = (float*)d_out;
    char* ws = (char*)d_ws;

    float*  WTq    = (float*) (ws + WS_WTQ);
    float*  WTv    = (float*) (ws + WS_WTV);
    float*  sqF    = (float*) (ws + WS_SQF);
    float*  xT     = (float*) (ws + WS_XT);
    float*  qT     = (float*) (ws + WS_QT);
    float*  vxT    = (float*) (ws + WS_VXT);
    int*    knn    = (int*)   (ws + WS_KNN);
    float*  attnF  = (float*) (ws + WS_ATTNF);
    float*  stdF   = (float*) (ws + WS_STD);
    float*  score  = (float*) (ws + WS_SCORE);
    int*    counts = (int*)   (ws + WS_COUNTS);
    int*    off    = (int*)   (ws + WS_OFF);
    int*    slots  = (int*)   (ws + WS_SLOTS);
    int*    chunkC = (int*)   (ws + WS_CHUNK);
    int*    selds  = (int*)   (ws + WS_SELDS);
    int*    seldr  = (int*)   (ws + WS_SELDR);

    hipLaunchKernelGGL(k_transposeW, dim3(CC), dim3(CC), 0, stream, Wq, Wv, WTq, WTv);
    hipLaunchKernelGGL(k_transposeX, dim3(NN/32, CC/32, BB), dim3(256), 0, stream, x, xT);
    hipLaunchKernelGGL(k_sq, dim3((BB*NN + 255)/256), dim3(256), 0, stream, xT, sqF);
    hipLaunchKernelGGL(k_proj, dim3(BB*NN), dim3(CC), 0, stream, xT, WTq, WTv, qT, vxT);
    hipLaunchKernelGGL(k_knn, dim3(BB*NN/GN), dim3(256), 0, stream, x, xT, sqF, knn);
    hipLaunchKernelGGL(k_energy, dim3(BB*NN), dim3(CC), 0, stream, xT, qT, Wk, knn, attnF, stdF);

    hipMemsetAsync(counts, 0, BB*NN*4, stream);
    hipLaunchKernelGGL(k_count, dim3((BB*NN*KNB + 255)/256), dim3(256), 0, stream, knn, counts);
    hipLaunchKernelGGL(k_scan, dim3(BB), dim3(256), 0, stream, counts, off);
    hipLaunchKernelGGL(k_chunkcount, dim3(BB*NCHUNK), dim3(256), 0, stream, knn, chunkC);
    hipLaunchKernelGGL(k_chunkscan, dim3((BB*NN + 255)/256), dim3(256), 0, stream, chunkC);
    hipLaunchKernelGGL(k_fill2, dim3(BB*NCHUNK), dim3(256), 0, stream, knn, off, chunkC, slots);
    hipLaunchKernelGGL(k_segsum, dim3((BB*NN + 255)/256), dim3(256), 0, stream, off, counts, slots, attnF, score);

    hipLaunchKernelGGL(k_topsort2, dim3(2*BB), dim3(256), 0, stream, score, stdF, out, selds, seldr);

    hipLaunchKernelGGL(k_gather, dim3(BB*(MSEL + NDROP)/TJ), dim3(CC), 0, stream, vxT, attnF, knn, selds, seldr, out);
}

// Round 14
// 1344.675 us; speedup vs baseline: 32.3099x; 1.0558x over previous
//
#include <hip/hip_runtime.h>
#include <float.h>
#include <math.h>

#define BB 2
#define CC 128
#define NN 4096
#define KNB 32
#define KSEL 40
#define GN 4
#define MSEL 2048
#define NDROP 2048
#define CHUNKSZ 1024
#define NCHUNK 128   // NN*KNB / CHUNKSZ per batch
#define TJ 16        // gather j-tile
#define KNNTHREADS 512

// ---------------- workspace layout (bytes) ----------------
#define WS_WTQ    0
#define WS_WTV    (WS_WTQ + CC*CC*4)
#define WS_SQF    (WS_WTV + CC*CC*4)                 // float[BB*NN]
#define WS_XT     (WS_SQF + BB*NN*4)                 // float[BB*NN*CC] (x transposed)
#define WS_QT     (WS_XT  + BB*NN*CC*4)              // float[BB*NN*CC]
#define WS_VXT    (WS_QT  + BB*NN*CC*4)              // float[BB*NN*CC]
#define WS_KNN    (WS_VXT + BB*NN*CC*4)              // int
#define WS_ATTNF  (WS_KNN + BB*NN*KNB*4)             // float
#define WS_STD    (WS_ATTNF + BB*NN*KNB*4)           // float[BB*NN]
#define WS_SCORE  (WS_STD + BB*NN*4)                 // float[BB*NN]
#define WS_COUNTS (WS_SCORE + BB*NN*4)
#define WS_OFF    (WS_COUNTS + BB*NN*4)
#define WS_SLOTS  (WS_OFF + BB*NN*4)
#define WS_CHUNK  (WS_SLOTS + BB*NN*KNB*4)           // int[BB][NCHUNK][NN] = 4MB
#define WS_SELDS  (WS_CHUNK + BB*NCHUNK*NN*4)
#define WS_SELDR  (WS_SELDS + BB*MSEL*4)
#define WS_END    (WS_SELDR + BB*NDROP*4)

// ---------------- output layout (floats) ----------------
#define OUT_XDS  0
#define OUT_IDX  (BB*CC*MSEL)
#define OUT_XDR  (OUT_IDX + BB*MSEL)
#define OUT_IDXD (OUT_XDR + BB*CC*NDROP)

// XLA:CPU-style sequential reduction over 32 contiguous fp32 (unfused adds).
__device__ __forceinline__ float seq32(const float* a) {
    float acc = a[0];
    #pragma unroll
    for (int i = 1; i < 32; ++i) acc = __fadd_rn(acc, a[i]);
    return acc;
}

// XLA lowers exp -> libm expf (nearly correctly rounded): emulate via double.
__device__ __forceinline__ float xla_expf(float x) {
    return (float)exp((double)x);
}

__global__ void k_transposeW(const float* __restrict__ Wq, const float* __restrict__ Wv,
                             float* __restrict__ WTq, float* __restrict__ WTv) {
    int c = blockIdx.x, o = threadIdx.x;
    WTq[c*CC + o] = Wq[o*CC + c];
    WTv[c*CC + o] = Wv[o*CC + c];
}

// x [b][c][n] -> xT [b][n][c] (LDS tile transpose; values untouched)
__global__ __launch_bounds__(256) void k_transposeX(const float* __restrict__ x,
                                                    float* __restrict__ xT) {
    __shared__ float t[32][33];
    int b  = blockIdx.z;
    int n0 = blockIdx.x * 32;
    int c0 = blockIdx.y * 32;
    int tx = threadIdx.x & 31, ty = threadIdx.x >> 5;  // 32 x 8
    const float* xb = x + (size_t)b*CC*NN;
    for (int r = ty; r < 32; r += 8)
        t[r][tx] = xb[(size_t)(c0+r)*NN + n0 + tx];
    __syncthreads();
    float* xo = xT + (size_t)b*NN*CC;
    for (int r = ty; r < 32; r += 8)
        xo[(size_t)(n0+r)*CC + c0 + tx] = t[tx][r];
}

// sqF: fp32 sequential over c (exact ref-emu; reads xT row contiguously).
__global__ void k_sq(const float* __restrict__ xT, float* __restrict__ sqF) {
    int i = blockIdx.x*blockDim.x + threadIdx.x;
    if (i >= BB*NN) return;
    const float* row = xT + (size_t)i*CC;
    float sf = 0.f;
    for (int c = 0; c < CC; ++c)
        sf = __fadd_rn(sf, __fmul_rn(row[c], row[c]));
    sqF[i] = sf;
}

// q: XLA-emu (sequential over c, FMA). v: plain fp32 (lenient outputs).
// (FROZEN)
__global__ __launch_bounds__(CC) void k_proj(const float* __restrict__ xT,
                                             const float* __restrict__ WTq,
                                             const float* __restrict__ WTv,
                                             float* __restrict__ qT,
                                             float* __restrict__ vxT) {
    int bn = blockIdx.x;
    int o = threadIdx.x;
    __shared__ float xs[CC];
    xs[o] = xT[(size_t)bn*CC + o];
    __syncthreads();
    float aq = 0.f, av = 0.f;
    for (int c = 0; c < CC; ++c) {
        float xv = xs[c];
        aq = fmaf(WTq[c*CC + o], xv, aq);
        av = fmaf(WTv[c*CC + o], xv, av);
    }
    size_t base = (size_t)bn*CC + o;
    qT[base] = aq; vxT[base] = av;
}

// KNN v5: 512-thread blocks (8 waves -> 4 waves/SIMD occupancy), thread owns
// 8 m's; fp32 gram with coalesced [c][n] loads + register accumulators;
// two-level cached argmin selection (waves 0-3, bit-identical to v4);
// exact re-rank by ref-emulated fp32 dist (FROZEN).
__global__ __launch_bounds__(KNNTHREADS) void k_knn(const float* __restrict__ x,
                                                    const float* __restrict__ xT,
                                                    const float* __restrict__ sqF,
                                                    int* __restrict__ knn) {
    __shared__ float xs[GN][CC];
    __shared__ float dist[GN][NN];
    __shared__ int   candIdx[GN][KSEL];
    __shared__ float candDist[GN][KSEL];
    int blk = blockIdx.x;
    int b  = blk / (NN/GN);
    int n0 = (blk % (NN/GN)) * GN;
    int tid = threadIdx.x;
    const float* xb  = x  + (size_t)b*CC*NN;
    const float* xbT = xT + (size_t)b*NN*CC;
    const float* sqf = sqF + b*NN;
    if (tid < GN*CC) {
        int g = tid / CC, c = tid % CC;
        xs[g][c] = xbT[(size_t)(n0+g)*CC + c];
    }
    __syncthreads();
    // ---- gram: thread owns m in [8*tid, 8*tid+8) as 2 float4 chunks ----
    float4 acc[GN][2];
    #pragma unroll
    for (int g = 0; g < GN; ++g)
        #pragma unroll
        for (int u = 0; u < 2; ++u)
            acc[g][u] = make_float4(0.f, 0.f, 0.f, 0.f);
    int m0 = tid * 8;
    #pragma unroll 4
    for (int c = 0; c < CC; ++c) {
        float q0 = xs[0][c], q1 = xs[1][c], q2 = xs[2][c], q3 = xs[3][c];
        const float4* row = (const float4*)(xb + (size_t)c*NN + m0);
        #pragma unroll
        for (int u = 0; u < 2; ++u) {
            float4 xv = row[u];
            acc[0][u].x += q0*xv.x; acc[0][u].y += q0*xv.y; acc[0][u].z += q0*xv.z; acc[0][u].w += q0*xv.w;
            acc[1][u].x += q1*xv.x; acc[1][u].y += q1*xv.y; acc[1][u].z += q1*xv.z; acc[1][u].w += q1*xv.w;
            acc[2][u].x += q2*xv.x; acc[2][u].y += q2*xv.y; acc[2][u].z += q2*xv.z; acc[2][u].w += q2*xv.w;
            acc[3][u].x += q3*xv.x; acc[3][u].y += q3*xv.y; acc[3][u].z += q3*xv.z; acc[3][u].w += q3*xv.w;
        }
    }
    {
        float sqn0 = sqf[n0+0], sqn1 = sqf[n0+1], sqn2 = sqf[n0+2], sqn3 = sqf[n0+3];
        const float4* sqm4 = (const float4*)(sqf + m0);
        #pragma unroll
        for (int u = 0; u < 2; ++u) {
            float4 sm = sqm4[u];
            float4 d0, d1, d2, d3;
            d0.x = sqn0 + sm.x - 2.f*acc[0][u].x; d0.y = sqn0 + sm.y - 2.f*acc[0][u].y;
            d0.z = sqn0 + sm.z - 2.f*acc[0][u].z; d0.w = sqn0 + sm.w - 2.f*acc[0][u].w;
            d1.x = sqn1 + sm.x - 2.f*acc[1][u].x; d1.y = sqn1 + sm.y - 2.f*acc[1][u].y;
            d1.z = sqn1 + sm.z - 2.f*acc[1][u].z; d1.w = sqn1 + sm.w - 2.f*acc[1][u].w;
            d2.x = sqn2 + sm.x - 2.f*acc[2][u].x; d2.y = sqn2 + sm.y - 2.f*acc[2][u].y;
            d2.z = sqn2 + sm.z - 2.f*acc[2][u].z; d2.w = sqn2 + sm.w - 2.f*acc[2][u].w;
            d3.x = sqn3 + sm.x - 2.f*acc[3][u].x; d3.y = sqn3 + sm.y - 2.f*acc[3][u].y;
            d3.z = sqn3 + sm.z - 2.f*acc[3][u].z; d3.w = sqn3 + sm.w - 2.f*acc[3][u].w;
            *(float4*)&dist[0][m0 + 4*u] = d0;
            *(float4*)&dist[1][m0 + 4*u] = d1;
            *(float4*)&dist[2][m0 + 4*u] = d2;
            *(float4*)&dist[3][m0 + 4*u] = d3;
        }
    }
    __syncthreads();
    // ---- selection on waves 0..GN-1 (identical to v4; lane owns m = lane+64i) ----
    int wid = tid >> 6, lane = tid & 63;
    if (wid < GN) {
        float* dr = dist[wid];
        float gmv[8]; int gmi[8];
        #pragma unroll
        for (int gi = 0; gi < 8; ++gi) {
            float bv = FLT_MAX; int bi = NN;
            #pragma unroll
            for (int i2 = 0; i2 < 8; ++i2) {
                int m = lane + 64*(gi*8 + i2);
                float v = dr[m];
                if (v < bv) { bv = v; bi = m; }
            }
            gmv[gi] = bv; gmi[gi] = bi;
        }
        for (int kk = 0; kk < KSEL; ++kk) {
            float lv = gmv[0]; int li = gmi[0];
            #pragma unroll
            for (int gi = 1; gi < 8; ++gi)
                if (gmv[gi] < lv || (gmv[gi] == lv && gmi[gi] < li)) { lv = gmv[gi]; li = gmi[gi]; }
            float bv = lv; int bi = li;
            for (int off = 32; off > 0; off >>= 1) {
                float ov = __shfl_xor(bv, off);
                int   oi = __shfl_xor(bi, off);
                if (ov < bv || (ov == bv && oi < bi)) { bv = ov; bi = oi; }
            }
            if (lane == 0) candIdx[wid][kk] = bi;
            if ((bi & 63) == lane) {
                dr[bi] = FLT_MAX;
                int gsel = (bi >> 6) >> 3;
                #pragma unroll
                for (int GI = 0; GI < 8; ++GI) if (GI == gsel) {
                    float bv2 = FLT_MAX; int bi2 = NN;
                    #pragma unroll
                    for (int i2 = 0; i2 < 8; ++i2) {
                        int m = lane + 64*(GI*8 + i2);
                        float v = dr[m];
                        if (v < bv2 || (v == bv2 && m < bi2)) { bv2 = v; bi2 = m; }
                    }
                    gmv[GI] = bv2; gmi[GI] = bi2;
                }
            }
        }
    }
    __syncthreads();
    // ---- re-rank by ref-emulated fp32 dist (sequential unfused; FROZEN) ----
    int g = wid, j = lane;
    if (g < GN && j < KSEL) {
        int m = candIdx[g][j];
        const float* colm = xbT + (size_t)m*CC;
        float acc2 = 0.f;
        for (int c = 0; c < CC; ++c)
            acc2 = __fadd_rn(acc2, __fmul_rn(xs[g][c], colm[c]));
        candDist[g][j] = __fsub_rn(__fadd_rn(sqf[n0+g], sqf[m]), __fmul_rn(2.0f, acc2));
    }
    __syncthreads();
    if (g < GN && j < KSEL) {
        float dme = candDist[g][j]; int ime = candIdx[g][j];
        int rank = 0;
        for (int t = 0; t < KSEL; ++t) {
            float dt = candDist[g][t]; int it = candIdx[g][t];
            if (dt < dme || (dt == dme && it < ime)) ++rank;
        }
        if (rank < KNB)
            knn[((size_t)b*NN + n0 + g)*KNB + rank] = ime;
    }
}

// XLA-emu of k = Wk @ (x_m - x_n), energy = q . k (sequential FMA), then
// softmax + std with SEQUENTIAL 32-length reductions (XLA reduce order).
// (round-11 verbatim — FROZEN)
__global__ __launch_bounds__(CC) void k_energy(const float* __restrict__ xT,
                                               const float* __restrict__ qT,
                                               const float* __restrict__ Wk,
                                               const int* __restrict__ knn,
                                               float* __restrict__ attnF,
                                               float* __restrict__ stdF) {
    int bn = blockIdx.x;
    int b = bn / NN;
    int o = threadIdx.x;
    __shared__ float xn[CC];
    __shared__ float qs[CC];
    __shared__ int   mIdx[KNB];
    __shared__ float nb[KNB][CC];
    __shared__ float kmat[KNB][CC];
    __shared__ float es[KNB];
    const float* xbT = xT + (size_t)b*NN*CC;
    xn[o] = xT[(size_t)bn*CC + o];
    qs[o] = qT[(size_t)bn*CC + o];
    if (o < KNB) mIdx[o] = knn[(size_t)bn*KNB + o];
    __syncthreads();
    #pragma unroll
    for (int kk = 0; kk < KNB; ++kk)
        nb[kk][o] = __fsub_rn(xbT[(size_t)mIdx[kk]*CC + o], xn[o]);
    __syncthreads();
    float acc[KNB];
    #pragma unroll
    for (int kk = 0; kk < KNB; ++kk) acc[kk] = 0.f;
    const float* wrow = Wk + (size_t)o*CC;
    for (int c = 0; c < CC; ++c) {
        float w = wrow[c];
        #pragma unroll
        for (int kk = 0; kk < KNB; ++kk)
            acc[kk] = fmaf(w, nb[kk][c], acc[kk]);
    }
    #pragma unroll
    for (int kk = 0; kk < KNB; ++kk) kmat[kk][o] = acc[kk];
    __syncthreads();
    if (o < KNB) {
        float e = 0.f;
        for (int d = 0; d < CC; ++d)
            e = fmaf(qs[d], kmat[o][d], e);
        es[o] = __fdiv_rn(e, __fsqrt_rn(128.0f));
    }
    __syncthreads();
    if (o == 0) {
        float mx = es[0];
        #pragma unroll
        for (int kk = 1; kk < KNB; ++kk) mx = fmaxf(mx, es[kk]);
        float p[KNB], a[KNB], d2[KNB];
        #pragma unroll
        for (int kk = 0; kk < KNB; ++kk)
            p[kk] = xla_expf(__fsub_rn(es[kk], mx));
        float s = seq32(p);
        #pragma unroll
        for (int kk = 0; kk < KNB; ++kk) {
            a[kk] = __fdiv_rn(p[kk], s);
            attnF[(size_t)bn*KNB + kk] = a[kk];
        }
        float mean = __fdiv_rn(seq32(a), 32.0f);
        #pragma unroll
        for (int kk = 0; kk < KNB; ++kk) {
            float dd = __fsub_rn(a[kk], mean);
            d2[kk] = __fmul_rn(dd, dd);
        }
        float var = __fdiv_rn(seq32(d2), 32.0f);
        stdF[bn] = __fsqrt_rn(var);
    }
}

__global__ void k_count(const int* __restrict__ knn, int* __restrict__ counts) {
    int i = blockIdx.x*blockDim.x + threadIdx.x;
    if (i >= BB*NN*KNB) return;
    int b = i / (NN*KNB);
    atomicAdd(&counts[b*NN + knn[i]], 1);
}

__global__ __launch_bounds__(256) void k_scan(const int* __restrict__ counts, int* __restrict__ off) {
    int b = blockIdx.x;
    const int* c = counts + b*NN;
    int* o = off + b*NN;
    __shared__ int part[256];
    __shared__ int partScan[256];
    int tid = threadIdx.x;
    int base = tid*16;
    int s = 0;
    for (int i = 0; i < 16; ++i) s += c[base+i];
    part[tid] = s;
    __syncthreads();
    if (tid == 0) { int a = 0; for (int i = 0; i < 256; ++i) { partScan[i] = a; a += part[i]; } }
    __syncthreads();
    int a = partScan[tid];
    for (int i = 0; i < 16; ++i) { o[base+i] = a; a += c[base+i]; }
}

// Per-chunk histogram over segment ids (deterministic; LDS atomics).
__global__ __launch_bounds__(256) void k_chunkcount(const int* __restrict__ knn,
                                                    int* __restrict__ chunkCnt) {
    __shared__ int hist[NN];
    int b = blockIdx.x / NCHUNK, p = blockIdx.x % NCHUNK;
    int tid = threadIdx.x;
    for (int i = tid; i < NN; i += 256) hist[i] = 0;
    __syncthreads();
    const int* kb = knn + (size_t)b*NN*KNB + (size_t)p*CHUNKSZ;
    for (int i = tid; i < CHUNKSZ; i += 256)
        atomicAdd(&hist[kb[i]], 1);
    __syncthreads();
    int* row = chunkCnt + ((size_t)b*NCHUNK + p)*NN;
    for (int i = tid; i < NN; i += 256) row[i] = hist[i];
}

// Per (b,m): exclusive scan of chunkCnt over chunks (in place).
__global__ __launch_bounds__(256) void k_chunkscan(int* __restrict__ chunkCnt) {
    int i = blockIdx.x*blockDim.x + threadIdx.x;
    if (i >= BB*NN) return;
    int b = i / NN, m = i % NN;
    int running = 0;
    for (int p = 0; p < NCHUNK; ++p) {
        size_t idx = ((size_t)b*NCHUNK + p)*NN + m;
        int t = chunkCnt[idx];
        chunkCnt[idx] = running;
        running += t;
    }
}

// Stable fill: local rank within chunk (#earlier same-m elements) + chunk base.
__global__ __launch_bounds__(256) void k_fill2(const int* __restrict__ knn,
                                               const int* __restrict__ off,
                                               const int* __restrict__ chunkCnt,
                                               int* __restrict__ slots) {
    __shared__ int mv[CHUNKSZ];
    int b = blockIdx.x / NCHUNK, p = blockIdx.x % NCHUNK;
    int tid = threadIdx.x;
    const int* kb = knn + (size_t)b*NN*KNB + (size_t)p*CHUNKSZ;
    for (int i = tid; i < CHUNKSZ; i += 256) mv[i] = kb[i];
    __syncthreads();
    const int* cbase = chunkCnt + ((size_t)b*NCHUNK + p)*NN;
    const int* ob    = off + b*NN;
    int* sb = slots + (size_t)b*NN*KNB;
    for (int i = tid; i < CHUNKSZ; i += 256) {
        int m = mv[i];
        int rank = 0;
        for (int j = 0; j < i; ++j) rank += (mv[j] == m);
        sb[ob[m] + cbase[m] + rank] = p*CHUNKSZ + i;
    }
}

// Segment sum in ascending (n,k) order, sequential fp32 unfused adds.
__global__ void k_segsum(const int* __restrict__ off, const int* __restrict__ counts,
                         const int* __restrict__ slots, const float* __restrict__ attn,
                         float* __restrict__ score) {
    int i = blockIdx.x*blockDim.x + threadIdx.x;
    if (i >= BB*NN) return;
    int b = i / NN;
    int o = off[i], cnt = counts[i];
    const int* s = slots + (size_t)b*NN*KNB + o;
    const float* ab = attn + (size_t)b*NN*KNB;
    float acc = 0.f;
    for (int a = 0; a < cnt; ++a) acc = __fadd_rn(acc, ab[s[a]]);
    score[i] = acc;
}

// Merged bitonic sorts: blocks [0,BB) sort score DESC; [BB,2BB) sort std ASC.
__global__ __launch_bounds__(256) void k_topsort2(const float* __restrict__ score,
                                                  const float* __restrict__ stdv,
                                                  float* __restrict__ out,
                                                  int* __restrict__ selds,
                                                  int* __restrict__ seldr) {
    int blk = blockIdx.x;
    bool desc = blk < BB;
    int b = desc ? blk : blk - BB;
    const float* val = (desc ? score : stdv) + b*NN;
    __shared__ float v[NN];
    __shared__ int  id[NN];
    for (int i = threadIdx.x; i < NN; i += 256) { v[i] = val[i]; id[i] = i; }
    __syncthreads();
    for (int k = 2; k <= NN; k <<= 1) {
        for (int j = k >> 1; j > 0; j >>= 1) {
            for (int i = threadIdx.x; i < NN; i += 256) {
                int ixj = i ^ j;
                if (ixj > i) {
                    float va = v[i], vb = v[ixj];
                    int ia = id[i], ib = id[ixj];
                    bool before = desc ? (va > vb || (va == vb && ia < ib))
                                       : (va < vb || (va == vb && ia < ib));
                    bool up = ((i & k) == 0);
                    if (up ? !before : before) {
                        v[i] = vb; v[ixj] = va; id[i] = ib; id[ixj] = ia;
                    }
                }
            }
            __syncthreads();
        }
    }
    float* idx_out = out + (desc ? OUT_IDX : OUT_IDXD) + b*MSEL;
    int*   sel_out = (desc ? selds : seldr) + b*MSEL;
    for (int i = threadIdx.x; i < MSEL; i += 256) {
        idx_out[i] = (float)id[i];
        sel_out[i] = id[i];
    }
}

// Tiled gather: block handles TJ selected columns; LDS tile then coalesced writes.
__global__ __launch_bounds__(CC) void k_gather(const float* __restrict__ vxT,
                                               const float* __restrict__ attn,
                                               const int* __restrict__ knn,
                                               const int* __restrict__ sel_ds,
                                               const int* __restrict__ sel_dr,
                                               float* __restrict__ out) {
    __shared__ float a_s[TJ][KNB];
    __shared__ int   m_s[TJ][KNB];
    __shared__ int   nsel_s[TJ];
    __shared__ float tile[TJ][CC];
    int blk = blockIdx.x;
    int c = threadIdx.x;
    const int blocksPerSel = BB*MSEL/TJ;
    bool dropped = false;
    if (blk >= blocksPerSel) { dropped = true; blk -= blocksPerSel; }
    int b  = blk / (MSEL/TJ);
    int j0 = (blk % (MSEL/TJ)) * TJ;
    const int* sel = (dropped ? sel_dr : sel_ds) + b*MSEL;
    if (c < TJ) nsel_s[c] = sel[j0 + c];
    __syncthreads();
    for (int i = c; i < TJ*KNB; i += CC) {
        int j = i / KNB, k = i % KNB;
        int ns = nsel_s[j];
        a_s[j][k] = attn[((size_t)b*NN + ns)*KNB + k];
        m_s[j][k] = knn [((size_t)b*NN + ns)*KNB + k];
    }
    __syncthreads();
    const float* vb = vxT + (size_t)b*NN*CC;
    for (int j = 0; j < TJ; ++j) {
        float vn = vb[(size_t)nsel_s[j]*CC + c];
        float acc = 0.f;
        #pragma unroll
        for (int k = 0; k < KNB; ++k)
            acc += a_s[j][k] * (vb[(size_t)m_s[j][k]*CC + c] - vn);
        tile[j][c] = acc;
    }
    __syncthreads();
    float* obase = out + (dropped ? OUT_XDR : OUT_XDS);
    for (int w = c; w < TJ*CC; w += CC) {
        int j = w & (TJ-1);
        int cc = w >> 4;   // log2(TJ)=4
        obase[((size_t)b*CC + cc)*MSEL + j0 + j] = tile[j][cc];
    }
}

extern "C" void kernel_launch(void* const* d_in, const int* in_sizes, int n_in,
                              void* d_out, int out_size, void* d_ws, size_t ws_size,
                              hipStream_t stream) {
    const float* x  = (const float*)d_in[0];
    const float* Wq = (const float*)d_in[1];
    const float* Wk = (const float*)d_in[2];
    const float* Wv = (const float*)d_in[3];
    float* out = (float*)d_out;
    char* ws = (char*)d_ws;

    float*  WTq    = (float*) (ws + WS_WTQ);
    float*  WTv    = (float*) (ws + WS_WTV);
    float*  sqF    = (float*) (ws + WS_SQF);
    float*  xT     = (float*) (ws + WS_XT);
    float*  qT     = (float*) (ws + WS_QT);
    float*  vxT    = (float*) (ws + WS_VXT);
    int*    knn    = (int*)   (ws + WS_KNN);
    float*  attnF  = (float*) (ws + WS_ATTNF);
    float*  stdF   = (float*) (ws + WS_STD);
    float*  score  = (float*) (ws + WS_SCORE);
    int*    counts = (int*)   (ws + WS_COUNTS);
    int*    off    = (int*)   (ws + WS_OFF);
    int*    slots  = (int*)   (ws + WS_SLOTS);
    int*    chunkC = (int*)   (ws + WS_CHUNK);
    int*    selds  = (int*)   (ws + WS_SELDS);
    int*    seldr  = (int*)   (ws + WS_SELDR);

    hipLaunchKernelGGL(k_transposeW, dim3(CC), dim3(CC), 0, stream, Wq, Wv, WTq, WTv);
    hipLaunchKernelGGL(k_transposeX, dim3(NN/32, CC/32, BB), dim3(256), 0, stream, x, xT);
    hipLaunchKernelGGL(k_sq, dim3((BB*NN + 255)/256), dim3(256), 0, stream, xT, sqF);
    hipLaunchKernelGGL(k_proj, dim3(BB*NN), dim3(CC), 0, stream, xT, WTq, WTv, qT, vxT);
    hipLaunchKernelGGL(k_knn, dim3(BB*NN/GN), dim3(KNNTHREADS), 0, stream, x, xT, sqF, knn);
    hipLaunchKernelGGL(k_energy, dim3(BB*NN), dim3(CC), 0, stream, xT, qT, Wk, knn, attnF, stdF);

    hipMemsetAsync(counts, 0, BB*NN*4, stream);
    hipLaunchKernelGGL(k_count, dim3((BB*NN*KNB + 255)/256), dim3(256), 0, stream, knn, counts);
    hipLaunchKernelGGL(k_scan, dim3(BB), dim3(256), 0, stream, counts, off);
    hipLaunchKernelGGL(k_chunkcount, dim3(BB*NCHUNK), dim3(256), 0, stream, knn, chunkC);
    hipLaunchKernelGGL(k_chunkscan, dim3((BB*NN + 255)/256), dim3(256), 0, stream, chunkC);
    hipLaunchKernelGGL(k_fill2, dim3(BB*NCHUNK), dim3(256), 0, stream, knn, off, chunkC, slots);
    hipLaunchKernelGGL(k_segsum, dim3((BB*NN + 255)/256), dim3(256), 0, stream, off, counts, slots, attnF, score);

    hipLaunchKernelGGL(k_topsort2, dim3(2*BB), dim3(256), 0, stream, score, stdF, out, selds, seldr);

    hipLaunchKernelGGL(k_gather, dim3(BB*(MSEL + NDROP)/TJ), dim3(CC), 0, stream, vxT, attnF, knn, selds, seldr, out);
}